// Round 1
// baseline (5720.365 us; speedup 1.0000x reference)
//
#include <hip/hip_runtime.h>
#include <hip/hip_bf16.h>
#include <math.h>

#define BQ 2
#define LQ 2048
#define D_MODEL 1024
#define D_INNER 2048
#define D_STATE 16
#define DT_RANK 64
#define D_CONV 4
#define DEPTH 2

// ---------------------------------------------------------------- LayerNorm
__global__ __launch_bounds__(256) void layernorm_kernel(
    const float* __restrict__ x, const float* __restrict__ w,
    const float* __restrict__ b, float* __restrict__ out)
{
    __shared__ float red[8];
    int row = blockIdx.x;
    const float* xr = x + (size_t)row * D_MODEL;
    float v[4];
    float s = 0.f, sq = 0.f;
#pragma unroll
    for (int i = 0; i < 4; ++i) {
        v[i] = xr[threadIdx.x + i * 256];
        s += v[i];
        sq += v[i] * v[i];
    }
#pragma unroll
    for (int off = 32; off; off >>= 1) {
        s += __shfl_down(s, off, 64);
        sq += __shfl_down(sq, off, 64);
    }
    int wid = threadIdx.x >> 6, lane = threadIdx.x & 63;
    if (!lane) { red[wid] = s; red[4 + wid] = sq; }
    __syncthreads();
    s = red[0] + red[1] + red[2] + red[3];
    sq = red[4] + red[5] + red[6] + red[7];
    float mu = s * (1.f / D_MODEL);
    float var = sq * (1.f / D_MODEL) - mu * mu;
    float rstd = rsqrtf(var + 1e-5f);
#pragma unroll
    for (int i = 0; i < 4; ++i) {
        int c = threadIdx.x + i * 256;
        out[(size_t)row * D_MODEL + c] = (v[i] - mu) * rstd * w[c] + b[c];
    }
}

// ---------------------------------------------------------------- GEMM (f32)
// C[M,N] = A[M,K] @ W[N,K]^T ; A row stride = lda ; W row stride = K ; C row stride = N
// epilogue 0: none; 1: softplus(acc + bias[n])
__global__ __launch_bounds__(256) void gemm_nt_kernel(
    const float* __restrict__ A, const float* __restrict__ W,
    float* __restrict__ C, int M, int N, int K, int lda,
    const float* __restrict__ bias, int epilogue)
{
    __shared__ float As[16][64];
    __shared__ float Ws[16][64];
    int tid = threadIdx.x;
    int tx = tid & 15, ty = tid >> 4;
    int bm = blockIdx.y * 64;
    int bn = blockIdx.x * 64;
    int lr = tid >> 2;          // 0..63 row within tile
    int lk = (tid & 3) * 4;     // k offset
    float acc[4][4] = {};

    for (int k0 = 0; k0 < K; k0 += 16) {
        {
            const float* src = A + (size_t)(bm + lr) * lda + k0 + lk;
            float4 v = *(const float4*)src;
            As[lk + 0][lr] = v.x; As[lk + 1][lr] = v.y;
            As[lk + 2][lr] = v.z; As[lk + 3][lr] = v.w;
        }
        {
            int n = bn + lr;
            float4 v = make_float4(0.f, 0.f, 0.f, 0.f);
            if (n < N) v = *(const float4*)(W + (size_t)n * K + k0 + lk);
            Ws[lk + 0][lr] = v.x; Ws[lk + 1][lr] = v.y;
            Ws[lk + 2][lr] = v.z; Ws[lk + 3][lr] = v.w;
        }
        __syncthreads();
#pragma unroll
        for (int k = 0; k < 16; ++k) {
            float4 a = *(const float4*)&As[k][ty * 4];
            float4 w = *(const float4*)&Ws[k][tx * 4];
            float av[4] = {a.x, a.y, a.z, a.w};
            float wv[4] = {w.x, w.y, w.z, w.w};
#pragma unroll
            for (int i = 0; i < 4; ++i)
#pragma unroll
                for (int j = 0; j < 4; ++j)
                    acc[i][j] += av[i] * wv[j];
        }
        __syncthreads();
    }

#pragma unroll
    for (int i = 0; i < 4; ++i) {
        int row = bm + ty * 4 + i;
#pragma unroll
        for (int j = 0; j < 4; ++j) {
            int col = bn + tx * 4 + j;
            if (col < N) {
                float v = acc[i][j];
                if (epilogue == 1) {
                    v += bias[col];
                    v = (v > 20.f) ? v : log1pf(expf(v));
                }
                C[(size_t)row * N + col] = v;
            }
        }
    }
}

// ------------------------------------------------------- causal conv + SiLU
__global__ __launch_bounds__(256) void conv_silu_kernel(
    const float* __restrict__ u, float* __restrict__ out,
    const float* __restrict__ w, const float* __restrict__ bias)
{
    int idx = blockIdx.x * 256 + threadIdx.x;   // < B*L*D_INNER
    int c = idx & (D_INNER - 1);
    int bl = idx / D_INNER;
    int l = bl & (LQ - 1);
    int b = bl / LQ;
    float acc = bias[c];
#pragma unroll
    for (int k = 0; k < D_CONV; ++k) {
        int ls = l - (D_CONV - 1) + k;
        if (ls >= 0)
            acc += u[((size_t)b * LQ + ls) * D_INNER + c] * w[c * D_CONV + k];
    }
    out[idx] = acc / (1.f + expf(-acc));
}

// ---------------------------------------------------------- selective scan
__global__ __launch_bounds__(64) void scan_kernel(
    const float* __restrict__ u, float* __restrict__ y,
    const float* __restrict__ dt, const float* __restrict__ xdbl,
    const float* __restrict__ A_log, const float* __restrict__ Dp)
{
    int gid = blockIdx.x * 64 + threadIdx.x;    // 0..B*D_INNER-1
    int b = gid / D_INNER;
    int d = gid & (D_INNER - 1);
    float A[D_STATE], h[D_STATE];
#pragma unroll
    for (int n = 0; n < D_STATE; ++n) {
        A[n] = -expf(A_log[(size_t)d * D_STATE + n]);
        h[n] = 0.f;
    }
    float Dd = Dp[d];
    const float* up = u + (size_t)b * LQ * D_INNER + d;
    const float* dtp = dt + (size_t)b * LQ * D_INNER + d;
    const float* xp = xdbl + (size_t)b * LQ * 96;
    float* yp = y + (size_t)b * LQ * D_INNER + d;

    for (int l = 0; l < LQ; ++l) {
        float uv = up[(size_t)l * D_INNER];
        float dtv = dtp[(size_t)l * D_INNER];
        float du = dtv * uv;
        const float* xr = xp + l * 96;
        float acc = 0.f;
#pragma unroll
        for (int n = 0; n < D_STATE; ++n) {
            float Bn = xr[DT_RANK + n];
            float Cn = xr[DT_RANK + D_STATE + n];
            float dA = expf(dtv * A[n]);
            h[n] = dA * h[n] + du * Bn;
            acc += h[n] * Cn;
        }
        yp[(size_t)l * D_INNER] = acc + uv * Dd;
    }
}

// ------------------------------------------------------------- SiLU gating
__global__ __launch_bounds__(256) void gate_kernel(
    float* __restrict__ y, const float* __restrict__ z)
{
    int i = blockIdx.x * 256 + threadIdx.x;
    float zv = z[i];
    y[i] *= zv / (1.f + expf(-zv));
}

// ---------------------------------------------------------------- launcher
extern "C" void kernel_launch(void* const* d_in, const int* in_sizes, int n_in,
                              void* d_out, int out_size, void* d_ws, size_t ws_size,
                              hipStream_t stream)
{
    const float* x        = (const float*)d_in[0];
    const float* norm_w   = (const float*)d_in[2];
    const float* norm_b   = (const float*)d_in[3];
    const float* in_proj  = (const float*)d_in[4];
    const float* conv_w   = (const float*)d_in[5];
    const float* conv_b   = (const float*)d_in[6];
    const float* x_proj   = (const float*)d_in[7];
    const float* dt_proj  = (const float*)d_in[8];
    const float* dt_projb = (const float*)d_in[9];
    const float* A_log    = (const float*)d_in[10];
    const float* Dp       = (const float*)d_in[11];
    const float* out_proj = (const float*)d_in[12];
    float* out = (float*)d_out;
    float* ws  = (float*)d_ws;

    const size_t BL   = (size_t)BQ * LQ;            // 4096
    const size_t BLDM = BL * D_MODEL;               // 4.19M
    const size_t BLDI = BL * D_INNER;               // 8.39M

    size_t o = 0;
    float* hn    = ws + o; o += BLDM;
    float* u_raw = ws + o; o += BLDI;
    float* zb    = ws + o; o += BLDI;
    float* uc    = ws + o; o += BLDI;
    float* xdbl  = ws + o; o += BL * 96;
    float* h1    = ws + o; o += BLDM;
    float* dtb   = u_raw;  // reuse: u_raw dead after conv

    for (int layer = 0; layer < DEPTH; ++layer) {
        const float* src = (layer == 0) ? x : h1;
        float* dst = (layer == DEPTH - 1) ? out : h1;

        layernorm_kernel<<<(int)BL, 256, 0, stream>>>(
            src, norm_w + (size_t)layer * D_MODEL, norm_b + (size_t)layer * D_MODEL, hn);

        const float* Wi = in_proj + (size_t)layer * 2 * D_INNER * D_MODEL;
        gemm_nt_kernel<<<dim3(D_INNER / 64, BL / 64), 256, 0, stream>>>(
            hn, Wi, u_raw, (int)BL, D_INNER, D_MODEL, D_MODEL, nullptr, 0);
        gemm_nt_kernel<<<dim3(D_INNER / 64, BL / 64), 256, 0, stream>>>(
            hn, Wi + (size_t)D_INNER * D_MODEL, zb, (int)BL, D_INNER, D_MODEL, D_MODEL, nullptr, 0);

        conv_silu_kernel<<<(int)(BLDI / 256), 256, 0, stream>>>(
            u_raw, uc, conv_w + (size_t)layer * D_INNER * D_CONV,
            conv_b + (size_t)layer * D_INNER);

        gemm_nt_kernel<<<dim3(2, BL / 64), 256, 0, stream>>>(
            uc, x_proj + (size_t)layer * 96 * D_INNER, xdbl,
            (int)BL, 96, D_INNER, D_INNER, nullptr, 0);

        gemm_nt_kernel<<<dim3(D_INNER / 64, BL / 64), 256, 0, stream>>>(
            xdbl, dt_proj + (size_t)layer * D_INNER * DT_RANK, dtb,
            (int)BL, D_INNER, DT_RANK, 96,
            dt_projb + (size_t)layer * D_INNER, 1);

        scan_kernel<<<(BQ * D_INNER) / 64, 64, 0, stream>>>(
            uc, uc, dtb, xdbl,
            A_log + (size_t)layer * D_INNER * D_STATE, Dp + (size_t)layer * D_INNER);

        gate_kernel<<<(int)(BLDI / 256), 256, 0, stream>>>(uc, zb);

        gemm_nt_kernel<<<dim3(D_MODEL / 64, BL / 64), 256, 0, stream>>>(
            uc, out_proj + (size_t)layer * D_MODEL * D_INNER, dst,
            (int)BL, D_MODEL, D_INNER, D_INNER, nullptr, 0);
    }
}

// Round 2
// 2267.205 us; speedup vs baseline: 2.5231x; 2.5231x over previous
//
#include <hip/hip_runtime.h>
#include <hip/hip_bf16.h>
#include <math.h>

#define BQ 2
#define LQ 2048
#define D_MODEL 1024
#define D_INNER 2048
#define D_STATE 16
#define DT_RANK 64
#define D_CONV 4
#define DEPTH 2
#define NCHUNK 64
#define CHUNK 32   // LQ / NCHUNK

// ---------------------------------------------------------------- LayerNorm
__global__ __launch_bounds__(256) void layernorm_kernel(
    const float* __restrict__ x, const float* __restrict__ w,
    const float* __restrict__ b, float* __restrict__ out)
{
    __shared__ float red[8];
    int row = blockIdx.x;
    const float* xr = x + (size_t)row * D_MODEL;
    float v[4];
    float s = 0.f, sq = 0.f;
#pragma unroll
    for (int i = 0; i < 4; ++i) {
        v[i] = xr[threadIdx.x + i * 256];
        s += v[i];
        sq += v[i] * v[i];
    }
#pragma unroll
    for (int off = 32; off; off >>= 1) {
        s += __shfl_down(s, off, 64);
        sq += __shfl_down(sq, off, 64);
    }
    int wid = threadIdx.x >> 6, lane = threadIdx.x & 63;
    if (!lane) { red[wid] = s; red[4 + wid] = sq; }
    __syncthreads();
    s = red[0] + red[1] + red[2] + red[3];
    sq = red[4] + red[5] + red[6] + red[7];
    float mu = s * (1.f / D_MODEL);
    float var = sq * (1.f / D_MODEL) - mu * mu;
    float rstd = rsqrtf(var + 1e-5f);
#pragma unroll
    for (int i = 0; i < 4; ++i) {
        int c = threadIdx.x + i * 256;
        out[(size_t)row * D_MODEL + c] = (v[i] - mu) * rstd * w[c] + b[c];
    }
}

// ---------------------------------------------------------------- GEMM (f32)
__global__ __launch_bounds__(256) void gemm_nt_kernel(
    const float* __restrict__ A, const float* __restrict__ W,
    float* __restrict__ C, int M, int N, int K, int lda,
    const float* __restrict__ bias, int epilogue)
{
    __shared__ float As[16][64];
    __shared__ float Ws[16][64];
    int tid = threadIdx.x;
    int tx = tid & 15, ty = tid >> 4;
    int bm = blockIdx.y * 64;
    int bn = blockIdx.x * 64;
    int lr = tid >> 2;
    int lk = (tid & 3) * 4;
    float acc[4][4] = {};

    for (int k0 = 0; k0 < K; k0 += 16) {
        {
            const float* src = A + (size_t)(bm + lr) * lda + k0 + lk;
            float4 v = *(const float4*)src;
            As[lk + 0][lr] = v.x; As[lk + 1][lr] = v.y;
            As[lk + 2][lr] = v.z; As[lk + 3][lr] = v.w;
        }
        {
            int n = bn + lr;
            float4 v = make_float4(0.f, 0.f, 0.f, 0.f);
            if (n < N) v = *(const float4*)(W + (size_t)n * K + k0 + lk);
            Ws[lk + 0][lr] = v.x; Ws[lk + 1][lr] = v.y;
            Ws[lk + 2][lr] = v.z; Ws[lk + 3][lr] = v.w;
        }
        __syncthreads();
#pragma unroll
        for (int k = 0; k < 16; ++k) {
            float4 a = *(const float4*)&As[k][ty * 4];
            float4 w = *(const float4*)&Ws[k][tx * 4];
            float av[4] = {a.x, a.y, a.z, a.w};
            float wv[4] = {w.x, w.y, w.z, w.w};
#pragma unroll
            for (int i = 0; i < 4; ++i)
#pragma unroll
                for (int j = 0; j < 4; ++j)
                    acc[i][j] += av[i] * wv[j];
        }
        __syncthreads();
    }

#pragma unroll
    for (int i = 0; i < 4; ++i) {
        int row = bm + ty * 4 + i;
#pragma unroll
        for (int j = 0; j < 4; ++j) {
            int col = bn + tx * 4 + j;
            if (col < N) {
                float v = acc[i][j];
                if (epilogue == 1) {
                    v += bias[col];
                    v = (v > 20.f) ? v : log1pf(expf(v));
                }
                C[(size_t)row * N + col] = v;
            }
        }
    }
}

// ------------------------------------------------------- causal conv + SiLU
__global__ __launch_bounds__(256) void conv_silu_kernel(
    const float* __restrict__ u, float* __restrict__ out,
    const float* __restrict__ w, const float* __restrict__ bias)
{
    int idx = blockIdx.x * 256 + threadIdx.x;
    int c = idx & (D_INNER - 1);
    int bl = idx / D_INNER;
    int l = bl & (LQ - 1);
    int b = bl / LQ;
    float acc = bias[c];
#pragma unroll
    for (int k = 0; k < D_CONV; ++k) {
        int ls = l - (D_CONV - 1) + k;
        if (ls >= 0)
            acc += u[((size_t)b * LQ + ls) * D_INNER + c] * w[c * D_CONV + k];
    }
    out[idx] = acc / (1.f + expf(-acc));
}

// -------------------------------------------- selective scan, chunked 3-phase
// phase 1: per (b, chunk, d): local scan h0=0 -> P[n]=prod dA, F[n]=local final h
__global__ __launch_bounds__(256) void scan_phase1_kernel(
    const float* __restrict__ u, const float* __restrict__ dt,
    const float* __restrict__ xdbl, const float* __restrict__ A_log,
    float* __restrict__ Pbuf, float* __restrict__ Fbuf)
{
    int d = blockIdx.x * 256 + threadIdx.x;
    int c = blockIdx.y;
    int b = blockIdx.z;
    float A[D_STATE], h[D_STATE], P[D_STATE];
#pragma unroll
    for (int n = 0; n < D_STATE; ++n) {
        A[n] = -expf(A_log[(size_t)d * D_STATE + n]);
        h[n] = 0.f; P[n] = 1.f;
    }
    int l0 = c * CHUNK;
    const float* up  = u  + ((size_t)b * LQ + l0) * D_INNER + d;
    const float* dtp = dt + ((size_t)b * LQ + l0) * D_INNER + d;
    const float* xp  = xdbl + ((size_t)b * LQ + l0) * 96;

    for (int l = 0; l < CHUNK; ++l) {
        float uv  = up[(size_t)l * D_INNER];
        float dtv = dtp[(size_t)l * D_INNER];
        float du = dtv * uv;
        const float* xr = xp + l * 96;
#pragma unroll
        for (int n = 0; n < D_STATE; ++n) {
            float dA = expf(dtv * A[n]);
            P[n] *= dA;
            h[n] = dA * h[n] + du * xr[DT_RANK + n];
        }
    }
    size_t base = ((size_t)(b * NCHUNK + c) * D_STATE) * D_INNER + d;
#pragma unroll
    for (int n = 0; n < D_STATE; ++n) {
        Pbuf[base + (size_t)n * D_INNER] = P[n];
        Fbuf[base + (size_t)n * D_INNER] = h[n];
    }
}

// phase 2: per (b, n, d): sequential combine over chunks.
// Overwrites Fbuf[c] with the chunk's true INITIAL state.
__global__ __launch_bounds__(256) void scan_phase2_kernel(
    const float* __restrict__ Pbuf, float* __restrict__ Fbuf)
{
    int d = blockIdx.x * 256 + threadIdx.x;
    int n = blockIdx.y;
    int b = blockIdx.z;
    float hinit = 0.f;
    for (int c = 0; c < NCHUNK; ++c) {
        size_t idx = ((size_t)(b * NCHUNK + c) * D_STATE + n) * D_INNER + d;
        float P = Pbuf[idx];
        float F = Fbuf[idx];
        Fbuf[idx] = hinit;
        hinit = P * hinit + F;
    }
}

// phase 3: per (b, chunk, d): re-scan with true h_init, write y (in-place over u ok)
__global__ __launch_bounds__(256) void scan_phase3_kernel(
    const float* __restrict__ u, float* __restrict__ y,
    const float* __restrict__ dt, const float* __restrict__ xdbl,
    const float* __restrict__ A_log, const float* __restrict__ Dp,
    const float* __restrict__ Hinit)
{
    int d = blockIdx.x * 256 + threadIdx.x;
    int c = blockIdx.y;
    int b = blockIdx.z;
    float A[D_STATE], h[D_STATE];
    size_t base = ((size_t)(b * NCHUNK + c) * D_STATE) * D_INNER + d;
#pragma unroll
    for (int n = 0; n < D_STATE; ++n) {
        A[n] = -expf(A_log[(size_t)d * D_STATE + n]);
        h[n] = Hinit[base + (size_t)n * D_INNER];
    }
    float Dd = Dp[d];
    int l0 = c * CHUNK;
    const float* up  = u  + ((size_t)b * LQ + l0) * D_INNER + d;
    const float* dtp = dt + ((size_t)b * LQ + l0) * D_INNER + d;
    const float* xp  = xdbl + ((size_t)b * LQ + l0) * 96;
    float* yp = y + ((size_t)b * LQ + l0) * D_INNER + d;

    for (int l = 0; l < CHUNK; ++l) {
        float uv  = up[(size_t)l * D_INNER];
        float dtv = dtp[(size_t)l * D_INNER];
        float du = dtv * uv;
        const float* xr = xp + l * 96;
        float acc = 0.f;
#pragma unroll
        for (int n = 0; n < D_STATE; ++n) {
            float dA = expf(dtv * A[n]);
            h[n] = dA * h[n] + du * xr[DT_RANK + n];
            acc += h[n] * xr[DT_RANK + D_STATE + n];
        }
        yp[(size_t)l * D_INNER] = acc + uv * Dd;
    }
}

// ------------------------------------------------------------- SiLU gating
__global__ __launch_bounds__(256) void gate_kernel(
    float* __restrict__ y, const float* __restrict__ z)
{
    int i = blockIdx.x * 256 + threadIdx.x;
    float zv = z[i];
    y[i] *= zv / (1.f + expf(-zv));
}

// ---------------------------------------------------------------- launcher
extern "C" void kernel_launch(void* const* d_in, const int* in_sizes, int n_in,
                              void* d_out, int out_size, void* d_ws, size_t ws_size,
                              hipStream_t stream)
{
    const float* x        = (const float*)d_in[0];
    const float* norm_w   = (const float*)d_in[2];
    const float* norm_b   = (const float*)d_in[3];
    const float* in_proj  = (const float*)d_in[4];
    const float* conv_w   = (const float*)d_in[5];
    const float* conv_b   = (const float*)d_in[6];
    const float* x_proj   = (const float*)d_in[7];
    const float* dt_proj  = (const float*)d_in[8];
    const float* dt_projb = (const float*)d_in[9];
    const float* A_log    = (const float*)d_in[10];
    const float* Dp       = (const float*)d_in[11];
    const float* out_proj = (const float*)d_in[12];
    float* out = (float*)d_out;
    float* ws  = (float*)d_ws;

    const size_t BL   = (size_t)BQ * LQ;            // 4096
    const size_t BLDM = BL * D_MODEL;               // 4.19M
    const size_t BLDI = BL * D_INNER;               // 8.39M

    size_t o = 0;
    float* hn    = ws + o; o += BLDM;
    float* u_raw = ws + o; o += BLDI;
    float* zb    = ws + o; o += BLDI;
    float* uc    = ws + o; o += BLDI;
    float* xdbl  = ws + o; o += BL * 96;
    float* h1    = ws + o; o += BLDM;
    float* Fbuf  = ws + o; o += BLDM;   // B*NCHUNK*D_STATE*D_INNER == BLDM
    float* dtb   = u_raw;   // reuse: u_raw dead after conv
    float* Pbuf  = hn;      // reuse: hn dead after in_proj/x_proj GEMMs

    for (int layer = 0; layer < DEPTH; ++layer) {
        const float* src = (layer == 0) ? x : h1;
        float* dst = (layer == DEPTH - 1) ? out : h1;

        layernorm_kernel<<<(int)BL, 256, 0, stream>>>(
            src, norm_w + (size_t)layer * D_MODEL, norm_b + (size_t)layer * D_MODEL, hn);

        const float* Wi = in_proj + (size_t)layer * 2 * D_INNER * D_MODEL;
        gemm_nt_kernel<<<dim3(D_INNER / 64, BL / 64), 256, 0, stream>>>(
            hn, Wi, u_raw, (int)BL, D_INNER, D_MODEL, D_MODEL, nullptr, 0);
        gemm_nt_kernel<<<dim3(D_INNER / 64, BL / 64), 256, 0, stream>>>(
            hn, Wi + (size_t)D_INNER * D_MODEL, zb, (int)BL, D_INNER, D_MODEL, D_MODEL, nullptr, 0);

        conv_silu_kernel<<<(int)(BLDI / 256), 256, 0, stream>>>(
            u_raw, uc, conv_w + (size_t)layer * D_INNER * D_CONV,
            conv_b + (size_t)layer * D_INNER);

        gemm_nt_kernel<<<dim3(2, BL / 64), 256, 0, stream>>>(
            uc, x_proj + (size_t)layer * 96 * D_INNER, xdbl,
            (int)BL, 96, D_INNER, D_INNER, nullptr, 0);

        gemm_nt_kernel<<<dim3(D_INNER / 64, BL / 64), 256, 0, stream>>>(
            xdbl, dt_proj + (size_t)layer * D_INNER * DT_RANK, dtb,
            (int)BL, D_INNER, DT_RANK, 96,
            dt_projb + (size_t)layer * D_INNER, 1);

        const float* Al = A_log + (size_t)layer * D_INNER * D_STATE;
        scan_phase1_kernel<<<dim3(D_INNER / 256, NCHUNK, BQ), 256, 0, stream>>>(
            uc, dtb, xdbl, Al, Pbuf, Fbuf);
        scan_phase2_kernel<<<dim3(D_INNER / 256, D_STATE, BQ), 256, 0, stream>>>(
            Pbuf, Fbuf);
        scan_phase3_kernel<<<dim3(D_INNER / 256, NCHUNK, BQ), 256, 0, stream>>>(
            uc, uc, dtb, xdbl, Al, Dp + (size_t)layer * D_INNER, Fbuf);

        gate_kernel<<<(int)(BLDI / 256), 256, 0, stream>>>(uc, zb);

        gemm_nt_kernel<<<dim3(D_MODEL / 64, BL / 64), 256, 0, stream>>>(
            uc, out_proj + (size_t)layer * D_MODEL * D_INNER, dst,
            (int)BL, D_MODEL, D_INNER, D_INNER, nullptr, 0);
    }
}

// Round 3
// 1008.371 us; speedup vs baseline: 5.6729x; 2.2484x over previous
//
#include <hip/hip_runtime.h>
#include <hip/hip_bf16.h>
#include <math.h>

#define BQ 2
#define LQ 2048
#define D_MODEL 1024
#define D_INNER 2048
#define D_STATE 16
#define DT_RANK 64
#define D_CONV 4
#define DEPTH 2
#define NCHUNK 64
#define CHUNK 32

typedef __attribute__((ext_vector_type(8))) short short8v;  // 8 bf16 (4 VGPRs)
typedef __attribute__((ext_vector_type(4))) float f32x4;

__device__ __forceinline__ short f2bf(float f) {
    union { float f; unsigned u; } v; v.f = f;
    unsigned r = v.u + 0x7fffu + ((v.u >> 16) & 1u);   // RNE
    return (short)(r >> 16);
}

__device__ __forceinline__ void async16(void* lds, const void* gp) {
    __builtin_amdgcn_global_load_lds(
        (const __attribute__((address_space(1))) void*)gp,
        (__attribute__((address_space(3))) void*)lds, 16, 0, 0);
}

// ------------------------------------------------- LayerNorm (bf16 output)
__global__ __launch_bounds__(256) void layernorm_kernel(
    const float* __restrict__ x, const float* __restrict__ w,
    const float* __restrict__ b, short* __restrict__ out)
{
    __shared__ float red[8];
    int row = blockIdx.x;
    const float* xr = x + (size_t)row * D_MODEL;
    float v[4];
    float s = 0.f, sq = 0.f;
#pragma unroll
    for (int i = 0; i < 4; ++i) {
        v[i] = xr[threadIdx.x + i * 256];
        s += v[i];
        sq += v[i] * v[i];
    }
#pragma unroll
    for (int off = 32; off; off >>= 1) {
        s += __shfl_down(s, off, 64);
        sq += __shfl_down(sq, off, 64);
    }
    int wid = threadIdx.x >> 6, lane = threadIdx.x & 63;
    if (!lane) { red[wid] = s; red[4 + wid] = sq; }
    __syncthreads();
    s = red[0] + red[1] + red[2] + red[3];
    sq = red[4] + red[5] + red[6] + red[7];
    float mu = s * (1.f / D_MODEL);
    float var = sq * (1.f / D_MODEL) - mu * mu;
    float rstd = rsqrtf(var + 1e-5f);
#pragma unroll
    for (int i = 0; i < 4; ++i) {
        int c = threadIdx.x + i * 256;
        out[(size_t)row * D_MODEL + c] = f2bf((v[i] - mu) * rstd * w[c] + b[c]);
    }
}

// ------------------------------------------------ bf16 MFMA GEMM (m97 style)
// C[M,N] f32 = A[M,K] bf16 @ W[N,K]^T bf16. M,N multiples of 128; K of 32.
__global__ __launch_bounds__(256) void gemm_bf16_kernel(
    const short* __restrict__ A, const short* __restrict__ W,
    float* __restrict__ C, int M, int N, int K)
{
    __shared__ __align__(16) short As[128 * 32];
    __shared__ __align__(16) short Bs[128 * 32];
    int tid = threadIdx.x;
    int lane = tid & 63, wv = tid >> 6;
    int bm = blockIdx.y * 128, bn = blockIdx.x * 128;
    int wr = wv >> 1, wc = wv & 1;                 // 2x2 wave grid, 64x64 each

    f32x4 acc[4][4] = {};

    // staging: wave-uniform LDS base + lane*16B; per-lane global source
    const short* Ag = A + (size_t)(bm + wv * 16 + (lane >> 2)) * K + (lane & 3) * 8;
    const short* Bg = W + (size_t)(bn + wv * 16 + (lane >> 2)) * K + (lane & 3) * 8;
    short* As0 = &As[(wv * 16) * 32];
    short* As1 = &As[(64 + wv * 16) * 32];
    short* Bs0 = &Bs[(wv * 16) * 32];
    short* Bs1 = &Bs[(64 + wv * 16) * 32];
    size_t rowskip = (size_t)64 * K;

    int fr = lane & 15, fk = (lane >> 4) * 8;

    for (int k0 = 0; k0 < K; k0 += 32) {
        async16(As0, Ag + k0);
        async16(As1, Ag + rowskip + k0);
        async16(Bs0, Bg + k0);
        async16(Bs1, Bg + rowskip + k0);
        __syncthreads();                            // vmcnt(0) drain + barrier
        short8v af[4], bf[4];
#pragma unroll
        for (int i = 0; i < 4; ++i)
            af[i] = *(const short8v*)&As[(wr * 64 + i * 16 + fr) * 32 + fk];
#pragma unroll
        for (int j = 0; j < 4; ++j)
            bf[j] = *(const short8v*)&Bs[(wc * 64 + j * 16 + fr) * 32 + fk];
#pragma unroll
        for (int i = 0; i < 4; ++i)
#pragma unroll
            for (int j = 0; j < 4; ++j)
                acc[i][j] = __builtin_amdgcn_mfma_f32_16x16x32_bf16(
                    af[i], bf[j], acc[i][j], 0, 0, 0);
        __syncthreads();
    }

    int cr = (lane >> 4) * 4, cc = lane & 15;       // D: col=lane&15, row=(lane>>4)*4+q
#pragma unroll
    for (int i = 0; i < 4; ++i) {
#pragma unroll
        for (int q = 0; q < 4; ++q) {
            int row = bm + wr * 64 + i * 16 + cr + q;
            float* Cp = C + (size_t)row * N + bn + wc * 64 + cc;
#pragma unroll
            for (int j = 0; j < 4; ++j)
                Cp[j * 16] = acc[i][j][q];
        }
    }
}

// ---------------------------------------------------------------- GEMM (f32)
__global__ __launch_bounds__(256) void gemm_nt_kernel(
    const float* __restrict__ A, const float* __restrict__ W,
    float* __restrict__ C, int M, int N, int K, int lda,
    const float* __restrict__ bias, int epilogue)
{
    __shared__ float As[16][64];
    __shared__ float Ws[16][64];
    int tid = threadIdx.x;
    int tx = tid & 15, ty = tid >> 4;
    int bm = blockIdx.y * 64;
    int bn = blockIdx.x * 64;
    int lr = tid >> 2;
    int lk = (tid & 3) * 4;
    float acc[4][4] = {};

    for (int k0 = 0; k0 < K; k0 += 16) {
        {
            const float* src = A + (size_t)(bm + lr) * lda + k0 + lk;
            float4 v = *(const float4*)src;
            As[lk + 0][lr] = v.x; As[lk + 1][lr] = v.y;
            As[lk + 2][lr] = v.z; As[lk + 3][lr] = v.w;
        }
        {
            int n = bn + lr;
            float4 v = make_float4(0.f, 0.f, 0.f, 0.f);
            if (n < N) v = *(const float4*)(W + (size_t)n * K + k0 + lk);
            Ws[lk + 0][lr] = v.x; Ws[lk + 1][lr] = v.y;
            Ws[lk + 2][lr] = v.z; Ws[lk + 3][lr] = v.w;
        }
        __syncthreads();
#pragma unroll
        for (int k = 0; k < 16; ++k) {
            float4 a = *(const float4*)&As[k][ty * 4];
            float4 w = *(const float4*)&Ws[k][tx * 4];
            float av[4] = {a.x, a.y, a.z, a.w};
            float wv[4] = {w.x, w.y, w.z, w.w};
#pragma unroll
            for (int i = 0; i < 4; ++i)
#pragma unroll
                for (int j = 0; j < 4; ++j)
                    acc[i][j] += av[i] * wv[j];
        }
        __syncthreads();
    }

#pragma unroll
    for (int i = 0; i < 4; ++i) {
        int row = bm + ty * 4 + i;
#pragma unroll
        for (int j = 0; j < 4; ++j) {
            int col = bn + tx * 4 + j;
            if (col < N) {
                float v = acc[i][j];
                if (epilogue == 1) {
                    v += bias[col];
                    v = (v > 20.f) ? v : log1pf(expf(v));
                }
                C[(size_t)row * N + col] = v;
            }
        }
    }
}

// ------------------------------------------------------- causal conv + SiLU
__global__ __launch_bounds__(256) void conv_silu_kernel(
    const float* __restrict__ u, float* __restrict__ out,
    const float* __restrict__ w, const float* __restrict__ bias)
{
    int idx = blockIdx.x * 256 + threadIdx.x;
    int c = idx & (D_INNER - 1);
    int bl = idx / D_INNER;
    int l = bl & (LQ - 1);
    int b = bl / LQ;
    float acc = bias[c];
#pragma unroll
    for (int k = 0; k < D_CONV; ++k) {
        int ls = l - (D_CONV - 1) + k;
        if (ls >= 0)
            acc += u[((size_t)b * LQ + ls) * D_INNER + c] * w[c * D_CONV + k];
    }
    out[idx] = acc / (1.f + expf(-acc));
}

// -------------------------------------------- selective scan, chunked 3-phase
__global__ __launch_bounds__(256) void scan_phase1_kernel(
    const float* __restrict__ u, const float* __restrict__ dt,
    const float* __restrict__ xdbl, const float* __restrict__ A_log,
    float* __restrict__ Pbuf, float* __restrict__ Fbuf)
{
    int d = blockIdx.x * 256 + threadIdx.x;
    int c = blockIdx.y;
    int b = blockIdx.z;
    float A[D_STATE], h[D_STATE], P[D_STATE];
#pragma unroll
    for (int n = 0; n < D_STATE; ++n) {
        A[n] = -expf(A_log[(size_t)d * D_STATE + n]);
        h[n] = 0.f; P[n] = 1.f;
    }
    int l0 = c * CHUNK;
    const float* up  = u  + ((size_t)b * LQ + l0) * D_INNER + d;
    const float* dtp = dt + ((size_t)b * LQ + l0) * D_INNER + d;
    const float* xp  = xdbl + ((size_t)b * LQ + l0) * 96;

    for (int l = 0; l < CHUNK; ++l) {
        float uv  = up[(size_t)l * D_INNER];
        float dtv = dtp[(size_t)l * D_INNER];
        float du = dtv * uv;
        const float* xr = xp + l * 96;
#pragma unroll
        for (int n = 0; n < D_STATE; ++n) {
            float dA = expf(dtv * A[n]);
            P[n] *= dA;
            h[n] = dA * h[n] + du * xr[DT_RANK + n];
        }
    }
    size_t base = ((size_t)(b * NCHUNK + c) * D_STATE) * D_INNER + d;
#pragma unroll
    for (int n = 0; n < D_STATE; ++n) {
        Pbuf[base + (size_t)n * D_INNER] = P[n];
        Fbuf[base + (size_t)n * D_INNER] = h[n];
    }
}

__global__ __launch_bounds__(256) void scan_phase2_kernel(
    const float* __restrict__ Pbuf, float* __restrict__ Fbuf)
{
    int d = blockIdx.x * 256 + threadIdx.x;
    int n = blockIdx.y;
    int b = blockIdx.z;
    float hinit = 0.f;
    for (int c = 0; c < NCHUNK; ++c) {
        size_t idx = ((size_t)(b * NCHUNK + c) * D_STATE + n) * D_INNER + d;
        float P = Pbuf[idx];
        float F = Fbuf[idx];
        Fbuf[idx] = hinit;
        hinit = P * hinit + F;
    }
}

__global__ __launch_bounds__(256) void scan_phase3_kernel(
    const float* __restrict__ u, float* __restrict__ y,
    const float* __restrict__ dt, const float* __restrict__ xdbl,
    const float* __restrict__ A_log, const float* __restrict__ Dp,
    const float* __restrict__ Hinit)
{
    int d = blockIdx.x * 256 + threadIdx.x;
    int c = blockIdx.y;
    int b = blockIdx.z;
    float A[D_STATE], h[D_STATE];
    size_t base = ((size_t)(b * NCHUNK + c) * D_STATE) * D_INNER + d;
#pragma unroll
    for (int n = 0; n < D_STATE; ++n) {
        A[n] = -expf(A_log[(size_t)d * D_STATE + n]);
        h[n] = Hinit[base + (size_t)n * D_INNER];
    }
    float Dd = Dp[d];
    int l0 = c * CHUNK;
    const float* up  = u  + ((size_t)b * LQ + l0) * D_INNER + d;
    const float* dtp = dt + ((size_t)b * LQ + l0) * D_INNER + d;
    const float* xp  = xdbl + ((size_t)b * LQ + l0) * 96;
    float* yp = y + ((size_t)b * LQ + l0) * D_INNER + d;

    for (int l = 0; l < CHUNK; ++l) {
        float uv  = up[(size_t)l * D_INNER];
        float dtv = dtp[(size_t)l * D_INNER];
        float du = dtv * uv;
        const float* xr = xp + l * 96;
        float acc = 0.f;
#pragma unroll
        for (int n = 0; n < D_STATE; ++n) {
            float dA = expf(dtv * A[n]);
            h[n] = dA * h[n] + du * xr[DT_RANK + n];
            acc += h[n] * xr[DT_RANK + D_STATE + n];
        }
        yp[(size_t)l * D_INNER] = acc + uv * Dd;
    }
}

// --------------------------------------------------- f32 -> bf16 conversion
__global__ __launch_bounds__(256) void convert_bf16_kernel(
    const float* __restrict__ in, short* __restrict__ out)
{
    int i = (blockIdx.x * 256 + threadIdx.x) * 4;
    float4 v = *(const float4*)(in + i);
    short4 o = make_short4(f2bf(v.x), f2bf(v.y), f2bf(v.z), f2bf(v.w));
    *(short4*)(out + i) = o;
}

// --------------------------------------- gate y*silu(z), write bf16 for GEMM
__global__ __launch_bounds__(256) void gate_convert_kernel(
    const float* __restrict__ y, const float* __restrict__ z,
    short* __restrict__ out)
{
    int i = (blockIdx.x * 256 + threadIdx.x) * 4;
    float4 yv = *(const float4*)(y + i);
    float4 zv = *(const float4*)(z + i);
    short4 o;
    o.x = f2bf(yv.x * zv.x / (1.f + expf(-zv.x)));
    o.y = f2bf(yv.y * zv.y / (1.f + expf(-zv.y)));
    o.z = f2bf(yv.z * zv.z / (1.f + expf(-zv.z)));
    o.w = f2bf(yv.w * zv.w / (1.f + expf(-zv.w)));
    *(short4*)(out + i) = o;
}

// ---------------------------------------------------------------- launcher
extern "C" void kernel_launch(void* const* d_in, const int* in_sizes, int n_in,
                              void* d_out, int out_size, void* d_ws, size_t ws_size,
                              hipStream_t stream)
{
    const float* x        = (const float*)d_in[0];
    const float* norm_w   = (const float*)d_in[2];
    const float* norm_b   = (const float*)d_in[3];
    const float* in_proj  = (const float*)d_in[4];
    const float* conv_w   = (const float*)d_in[5];
    const float* conv_b   = (const float*)d_in[6];
    const float* x_proj   = (const float*)d_in[7];
    const float* dt_proj  = (const float*)d_in[8];
    const float* dt_projb = (const float*)d_in[9];
    const float* A_log    = (const float*)d_in[10];
    const float* Dp       = (const float*)d_in[11];
    const float* out_proj = (const float*)d_in[12];
    float* out = (float*)d_out;
    float* ws  = (float*)d_ws;

    const size_t BL   = (size_t)BQ * LQ;            // 4096
    const size_t BLDM = BL * D_MODEL;
    const size_t BLDI = BL * D_INNER;
    const int IN_W  = 2 * D_INNER * D_MODEL;        // 4.19M elems
    const int OUT_W = D_MODEL * D_INNER;            // 2.10M elems

    size_t o = 0;
    float* Pbuf  = ws + o; o += BLDM;   // scan P; earlier in layer: hnb (bf16)
    float* u_raw = ws + o; o += BLDI;   // in_proj u out; then dtb; then ucb (bf16)
    float* zb    = ws + o; o += BLDI;
    float* uc    = ws + o; o += BLDI;
    float* xdbl  = ws + o; o += BL * 96;
    float* h1    = ws + o; o += BLDM;
    float* Fbuf  = ws + o; o += BLDM;
    short* wbuf  = (short*)(ws + o); o += (size_t)(IN_W + OUT_W) / 2;

    short* hnb = (short*)Pbuf;   // dead before scan phase1 writes Pbuf
    float* dtb = u_raw;          // u_raw dead after conv
    short* ucb = (short*)u_raw;  // dtb dead after scan phase3

    for (int layer = 0; layer < DEPTH; ++layer) {
        const float* src = (layer == 0) ? x : h1;
        float* dst = (layer == DEPTH - 1) ? out : h1;

        convert_bf16_kernel<<<IN_W / 1024, 256, 0, stream>>>(
            in_proj + (size_t)layer * IN_W, wbuf);
        convert_bf16_kernel<<<OUT_W / 1024, 256, 0, stream>>>(
            out_proj + (size_t)layer * OUT_W, wbuf + IN_W);

        layernorm_kernel<<<(int)BL, 256, 0, stream>>>(
            src, norm_w + (size_t)layer * D_MODEL, norm_b + (size_t)layer * D_MODEL, hnb);

        gemm_bf16_kernel<<<dim3(D_INNER / 128, BL / 128), 256, 0, stream>>>(
            hnb, wbuf, u_raw, (int)BL, D_INNER, D_MODEL);
        gemm_bf16_kernel<<<dim3(D_INNER / 128, BL / 128), 256, 0, stream>>>(
            hnb, wbuf + (size_t)D_INNER * D_MODEL, zb, (int)BL, D_INNER, D_MODEL);

        conv_silu_kernel<<<(int)(BLDI / 256), 256, 0, stream>>>(
            u_raw, uc, conv_w + (size_t)layer * D_INNER * D_CONV,
            conv_b + (size_t)layer * D_INNER);

        gemm_nt_kernel<<<dim3(2, BL / 64), 256, 0, stream>>>(
            uc, x_proj + (size_t)layer * 96 * D_INNER, xdbl,
            (int)BL, 96, D_INNER, D_INNER, nullptr, 0);

        gemm_nt_kernel<<<dim3(D_INNER / 64, BL / 64), 256, 0, stream>>>(
            xdbl, dt_proj + (size_t)layer * D_INNER * DT_RANK, dtb,
            (int)BL, D_INNER, DT_RANK, 96,
            dt_projb + (size_t)layer * D_INNER, 1);

        const float* Al = A_log + (size_t)layer * D_INNER * D_STATE;
        scan_phase1_kernel<<<dim3(D_INNER / 256, NCHUNK, BQ), 256, 0, stream>>>(
            uc, dtb, xdbl, Al, Pbuf, Fbuf);
        scan_phase2_kernel<<<dim3(D_INNER / 256, D_STATE, BQ), 256, 0, stream>>>(
            Pbuf, Fbuf);
        scan_phase3_kernel<<<dim3(D_INNER / 256, NCHUNK, BQ), 256, 0, stream>>>(
            uc, uc, dtb, xdbl, Al, Dp + (size_t)layer * D_INNER, Fbuf);

        gate_convert_kernel<<<(int)(BLDI / 1024), 256, 0, stream>>>(uc, zb, ucb);

        gemm_bf16_kernel<<<dim3(D_MODEL / 128, BL / 128), 256, 0, stream>>>(
            ucb, wbuf + IN_W, dst, (int)BL, D_MODEL, D_INNER);
    }
}

// Round 4
// 802.110 us; speedup vs baseline: 7.1316x; 1.2571x over previous
//
#include <hip/hip_runtime.h>
#include <hip/hip_bf16.h>
#include <math.h>

#define BQ 2
#define LQ 2048
#define D_MODEL 1024
#define D_INNER 2048
#define D_STATE 16
#define DT_RANK 64
#define D_CONV 4
#define DEPTH 2
#define NCHUNK 64
#define CHUNK 32
#define XSPLITK 8
#define XKC (D_INNER / XSPLITK)   // 256

typedef __attribute__((ext_vector_type(8))) short short8v;  // 8 bf16 (4 VGPRs)
typedef __attribute__((ext_vector_type(4))) float f32x4;

__device__ __forceinline__ short f2bf(float f) {
    union { float f; unsigned u; } v; v.f = f;
    unsigned r = v.u + 0x7fffu + ((v.u >> 16) & 1u);   // RNE
    return (short)(r >> 16);
}

__device__ __forceinline__ void async16(void* lds, const void* gp) {
    __builtin_amdgcn_global_load_lds(
        (const __attribute__((address_space(1))) void*)gp,
        (__attribute__((address_space(3))) void*)lds, 16, 0, 0);
}

// ------------------------------------------------- LayerNorm (bf16 output)
__global__ __launch_bounds__(256) void layernorm_kernel(
    const float* __restrict__ x, const float* __restrict__ w,
    const float* __restrict__ b, short* __restrict__ out)
{
    __shared__ float red[8];
    int row = blockIdx.x;
    const float* xr = x + (size_t)row * D_MODEL;
    float v[4];
    float s = 0.f, sq = 0.f;
#pragma unroll
    for (int i = 0; i < 4; ++i) {
        v[i] = xr[threadIdx.x + i * 256];
        s += v[i];
        sq += v[i] * v[i];
    }
#pragma unroll
    for (int off = 32; off; off >>= 1) {
        s += __shfl_down(s, off, 64);
        sq += __shfl_down(sq, off, 64);
    }
    int wid = threadIdx.x >> 6, lane = threadIdx.x & 63;
    if (!lane) { red[wid] = s; red[4 + wid] = sq; }
    __syncthreads();
    s = red[0] + red[1] + red[2] + red[3];
    sq = red[4] + red[5] + red[6] + red[7];
    float mu = s * (1.f / D_MODEL);
    float var = sq * (1.f / D_MODEL) - mu * mu;
    float rstd = rsqrtf(var + 1e-5f);
#pragma unroll
    for (int i = 0; i < 4; ++i) {
        int c = threadIdx.x + i * 256;
        out[(size_t)row * D_MODEL + c] = f2bf((v[i] - mu) * rstd * w[c] + b[c]);
    }
}

// ------------------------------------------------ bf16 MFMA GEMM (m97 style)
__global__ __launch_bounds__(256) void gemm_bf16_kernel(
    const short* __restrict__ A, const short* __restrict__ W,
    float* __restrict__ C, int M, int N, int K)
{
    __shared__ __align__(16) short As[128 * 32];
    __shared__ __align__(16) short Bs[128 * 32];
    int tid = threadIdx.x;
    int lane = tid & 63, wv = tid >> 6;
    int bm = blockIdx.y * 128, bn = blockIdx.x * 128;
    int wr = wv >> 1, wc = wv & 1;

    f32x4 acc[4][4] = {};

    const short* Ag = A + (size_t)(bm + wv * 16 + (lane >> 2)) * K + (lane & 3) * 8;
    const short* Bg = W + (size_t)(bn + wv * 16 + (lane >> 2)) * K + (lane & 3) * 8;
    short* As0 = &As[(wv * 16) * 32];
    short* As1 = &As[(64 + wv * 16) * 32];
    short* Bs0 = &Bs[(wv * 16) * 32];
    short* Bs1 = &Bs[(64 + wv * 16) * 32];
    size_t rowskip = (size_t)64 * K;

    int fr = lane & 15, fk = (lane >> 4) * 8;

    for (int k0 = 0; k0 < K; k0 += 32) {
        async16(As0, Ag + k0);
        async16(As1, Ag + rowskip + k0);
        async16(Bs0, Bg + k0);
        async16(Bs1, Bg + rowskip + k0);
        __syncthreads();
        short8v af[4], bf[4];
#pragma unroll
        for (int i = 0; i < 4; ++i)
            af[i] = *(const short8v*)&As[(wr * 64 + i * 16 + fr) * 32 + fk];
#pragma unroll
        for (int j = 0; j < 4; ++j)
            bf[j] = *(const short8v*)&Bs[(wc * 64 + j * 16 + fr) * 32 + fk];
#pragma unroll
        for (int i = 0; i < 4; ++i)
#pragma unroll
            for (int j = 0; j < 4; ++j)
                acc[i][j] = __builtin_amdgcn_mfma_f32_16x16x32_bf16(
                    af[i], bf[j], acc[i][j], 0, 0, 0);
        __syncthreads();
    }

    int cr = (lane >> 4) * 4, cc = lane & 15;
#pragma unroll
    for (int i = 0; i < 4; ++i) {
#pragma unroll
        for (int q = 0; q < 4; ++q) {
            int row = bm + wr * 64 + i * 16 + cr + q;
            float* Cp = C + (size_t)row * N + bn + wc * 64 + cc;
#pragma unroll
            for (int j = 0; j < 4; ++j)
                Cp[j * 16] = acc[i][j][q];
        }
    }
}

// ------------------------- x_proj: tall-skinny split-K bf16 MFMA, no LDS
// A[BL][D_INNER] bf16, W[96][D_INNER] bf16 -> Xpart[XSPLITK][BL][96] f32
__global__ __launch_bounds__(256) void xproj_kernel(
    const short* __restrict__ A, const short* __restrict__ W,
    float* __restrict__ Xpart)
{
    int lane = threadIdx.x & 63, wv = threadIdx.x >> 6;
    int sk = blockIdx.x;
    int m0 = blockIdx.y * 64 + wv * 16;
    int fr = lane & 15, fk = (lane >> 4) * 8;
    const short* Ap = A + (size_t)(m0 + fr) * D_INNER + sk * XKC + fk;
    const short* Wp = W + (size_t)fr * D_INNER + sk * XKC + fk;
    f32x4 acc[6] = {};
    for (int k = 0; k < XKC; k += 32) {
        short8v af = *(const short8v*)(Ap + k);
#pragma unroll
        for (int j = 0; j < 6; ++j) {
            short8v bf = *(const short8v*)(Wp + (size_t)j * 16 * D_INNER + k);
            acc[j] = __builtin_amdgcn_mfma_f32_16x16x32_bf16(af, bf, acc[j], 0, 0, 0);
        }
    }
    int cr = (lane >> 4) * 4, cc = lane & 15;
    float* Op = Xpart + ((size_t)sk * (BQ * LQ) + m0 + cr) * 96 + cc;
#pragma unroll
    for (int j = 0; j < 6; ++j)
#pragma unroll
        for (int q = 0; q < 4; ++q)
            Op[(size_t)q * 96 + j * 16] = acc[j][q];
}

__global__ __launch_bounds__(256) void xreduce_kernel(
    const float* __restrict__ Xpart, float* __restrict__ xdbl)
{
    size_t i = (size_t)blockIdx.x * 256 + threadIdx.x;   // < BL*96
    float s = 0.f;
#pragma unroll
    for (int sk = 0; sk < XSPLITK; ++sk)
        s += Xpart[(size_t)sk * ((size_t)BQ * LQ * 96) + i];
    xdbl[i] = s;
}

// ---------------------------------------------------------------- GEMM (f32)
__global__ __launch_bounds__(256) void gemm_nt_kernel(
    const float* __restrict__ A, const float* __restrict__ W,
    float* __restrict__ C, int M, int N, int K, int lda,
    const float* __restrict__ bias, int epilogue)
{
    __shared__ float As[16][64];
    __shared__ float Ws[16][64];
    int tid = threadIdx.x;
    int tx = tid & 15, ty = tid >> 4;
    int bm = blockIdx.y * 64;
    int bn = blockIdx.x * 64;
    int lr = tid >> 2;
    int lk = (tid & 3) * 4;
    float acc[4][4] = {};

    for (int k0 = 0; k0 < K; k0 += 16) {
        {
            const float* src = A + (size_t)(bm + lr) * lda + k0 + lk;
            float4 v = *(const float4*)src;
            As[lk + 0][lr] = v.x; As[lk + 1][lr] = v.y;
            As[lk + 2][lr] = v.z; As[lk + 3][lr] = v.w;
        }
        {
            int n = bn + lr;
            float4 v = make_float4(0.f, 0.f, 0.f, 0.f);
            if (n < N) v = *(const float4*)(W + (size_t)n * K + k0 + lk);
            Ws[lk + 0][lr] = v.x; Ws[lk + 1][lr] = v.y;
            Ws[lk + 2][lr] = v.z; Ws[lk + 3][lr] = v.w;
        }
        __syncthreads();
#pragma unroll
        for (int k = 0; k < 16; ++k) {
            float4 a = *(const float4*)&As[k][ty * 4];
            float4 w = *(const float4*)&Ws[k][tx * 4];
            float av[4] = {a.x, a.y, a.z, a.w};
            float wv[4] = {w.x, w.y, w.z, w.w};
#pragma unroll
            for (int i = 0; i < 4; ++i)
#pragma unroll
                for (int j = 0; j < 4; ++j)
                    acc[i][j] += av[i] * wv[j];
        }
        __syncthreads();
    }

#pragma unroll
    for (int i = 0; i < 4; ++i) {
        int row = bm + ty * 4 + i;
#pragma unroll
        for (int j = 0; j < 4; ++j) {
            int col = bn + tx * 4 + j;
            if (col < N) {
                float v = acc[i][j];
                if (epilogue == 1) {
                    v += bias[col];
                    v = (v > 20.f) ? v : log1pf(expf(v));
                }
                C[(size_t)row * N + col] = v;
            }
        }
    }
}

// --------------------------- causal conv + SiLU (writes f32 + bf16 copies)
__global__ __launch_bounds__(256) void conv_silu_kernel(
    const float* __restrict__ u, float* __restrict__ out,
    short* __restrict__ outb, const float* __restrict__ w,
    const float* __restrict__ bias)
{
    int idx = blockIdx.x * 256 + threadIdx.x;
    int c = idx & (D_INNER - 1);
    int bl = idx / D_INNER;
    int l = bl & (LQ - 1);
    int b = bl / LQ;
    float acc = bias[c];
#pragma unroll
    for (int k = 0; k < D_CONV; ++k) {
        int ls = l - (D_CONV - 1) + k;
        if (ls >= 0)
            acc += u[((size_t)b * LQ + ls) * D_INNER + c] * w[c * D_CONV + k];
    }
    float val = acc / (1.f + expf(-acc));
    out[idx] = val;
    outb[idx] = f2bf(val);
}

// -------------------------------------------- selective scan, chunked 3-phase
__global__ __launch_bounds__(256) void scan_phase1_kernel(
    const float* __restrict__ u, const float* __restrict__ dt,
    const float* __restrict__ xdbl, const float* __restrict__ A_log,
    float* __restrict__ Pbuf, float* __restrict__ Fbuf)
{
    int d = blockIdx.x * 256 + threadIdx.x;
    int c = blockIdx.y;
    int b = blockIdx.z;
    float A[D_STATE], h[D_STATE], P[D_STATE];
#pragma unroll
    for (int n = 0; n < D_STATE; ++n) {
        A[n] = -expf(A_log[(size_t)d * D_STATE + n]);
        h[n] = 0.f; P[n] = 1.f;
    }
    int l0 = c * CHUNK;
    const float* up  = u  + ((size_t)b * LQ + l0) * D_INNER + d;
    const float* dtp = dt + ((size_t)b * LQ + l0) * D_INNER + d;
    const float* xp  = xdbl + ((size_t)b * LQ + l0) * 96;

    for (int l = 0; l < CHUNK; ++l) {
        float uv  = up[(size_t)l * D_INNER];
        float dtv = dtp[(size_t)l * D_INNER];
        float du = dtv * uv;
        const float* xr = xp + l * 96;
#pragma unroll
        for (int n = 0; n < D_STATE; ++n) {
            float dA = expf(dtv * A[n]);
            P[n] *= dA;
            h[n] = dA * h[n] + du * xr[DT_RANK + n];
        }
    }
    size_t base = ((size_t)(b * NCHUNK + c) * D_STATE) * D_INNER + d;
#pragma unroll
    for (int n = 0; n < D_STATE; ++n) {
        Pbuf[base + (size_t)n * D_INNER] = P[n];
        Fbuf[base + (size_t)n * D_INNER] = h[n];
    }
}

__global__ __launch_bounds__(256) void scan_phase2_kernel(
    const float* __restrict__ Pbuf, float* __restrict__ Fbuf)
{
    int d = blockIdx.x * 256 + threadIdx.x;
    int n = blockIdx.y;
    int b = blockIdx.z;
    float hinit = 0.f;
    for (int c = 0; c < NCHUNK; ++c) {
        size_t idx = ((size_t)(b * NCHUNK + c) * D_STATE + n) * D_INNER + d;
        float P = Pbuf[idx];
        float F = Fbuf[idx];
        Fbuf[idx] = hinit;
        hinit = P * hinit + F;
    }
}

__global__ __launch_bounds__(256) void scan_phase3_kernel(
    const float* __restrict__ u, float* __restrict__ y,
    const float* __restrict__ dt, const float* __restrict__ xdbl,
    const float* __restrict__ A_log, const float* __restrict__ Dp,
    const float* __restrict__ Hinit)
{
    int d = blockIdx.x * 256 + threadIdx.x;
    int c = blockIdx.y;
    int b = blockIdx.z;
    float A[D_STATE], h[D_STATE];
    size_t base = ((size_t)(b * NCHUNK + c) * D_STATE) * D_INNER + d;
#pragma unroll
    for (int n = 0; n < D_STATE; ++n) {
        A[n] = -expf(A_log[(size_t)d * D_STATE + n]);
        h[n] = Hinit[base + (size_t)n * D_INNER];
    }
    float Dd = Dp[d];
    int l0 = c * CHUNK;
    const float* up  = u  + ((size_t)b * LQ + l0) * D_INNER + d;
    const float* dtp = dt + ((size_t)b * LQ + l0) * D_INNER + d;
    const float* xp  = xdbl + ((size_t)b * LQ + l0) * 96;
    float* yp = y + ((size_t)b * LQ + l0) * D_INNER + d;

    for (int l = 0; l < CHUNK; ++l) {
        float uv  = up[(size_t)l * D_INNER];
        float dtv = dtp[(size_t)l * D_INNER];
        float du = dtv * uv;
        const float* xr = xp + l * 96;
        float acc = 0.f;
#pragma unroll
        for (int n = 0; n < D_STATE; ++n) {
            float dA = expf(dtv * A[n]);
            h[n] = dA * h[n] + du * xr[DT_RANK + n];
            acc += h[n] * xr[DT_RANK + D_STATE + n];
        }
        yp[(size_t)l * D_INNER] = acc + uv * Dd;
    }
}

// --------------------------------------------------- f32 -> bf16 conversion
__global__ __launch_bounds__(256) void convert_bf16_kernel(
    const float* __restrict__ in, short* __restrict__ out)
{
    int i = (blockIdx.x * 256 + threadIdx.x) * 4;
    float4 v = *(const float4*)(in + i);
    short4 o = make_short4(f2bf(v.x), f2bf(v.y), f2bf(v.z), f2bf(v.w));
    *(short4*)(out + i) = o;
}

// --------------------------------------- gate y*silu(z), write bf16 for GEMM
__global__ __launch_bounds__(256) void gate_convert_kernel(
    const float* __restrict__ y, const float* __restrict__ z,
    short* __restrict__ out)
{
    int i = (blockIdx.x * 256 + threadIdx.x) * 4;
    float4 yv = *(const float4*)(y + i);
    float4 zv = *(const float4*)(z + i);
    short4 o;
    o.x = f2bf(yv.x * zv.x / (1.f + expf(-zv.x)));
    o.y = f2bf(yv.y * zv.y / (1.f + expf(-zv.y)));
    o.z = f2bf(yv.z * zv.z / (1.f + expf(-zv.z)));
    o.w = f2bf(yv.w * zv.w / (1.f + expf(-zv.w)));
    *(short4*)(out + i) = o;
}

// ---------------------------------------------------------------- launcher
extern "C" void kernel_launch(void* const* d_in, const int* in_sizes, int n_in,
                              void* d_out, int out_size, void* d_ws, size_t ws_size,
                              hipStream_t stream)
{
    const float* x        = (const float*)d_in[0];
    const float* norm_w   = (const float*)d_in[2];
    const float* norm_b   = (const float*)d_in[3];
    const float* in_proj  = (const float*)d_in[4];
    const float* conv_w   = (const float*)d_in[5];
    const float* conv_b   = (const float*)d_in[6];
    const float* x_proj   = (const float*)d_in[7];
    const float* dt_proj  = (const float*)d_in[8];
    const float* dt_projb = (const float*)d_in[9];
    const float* A_log    = (const float*)d_in[10];
    const float* Dp       = (const float*)d_in[11];
    const float* out_proj = (const float*)d_in[12];
    float* out = (float*)d_out;
    float* ws  = (float*)d_ws;

    const size_t BL   = (size_t)BQ * LQ;            // 4096
    const size_t BLDM = BL * D_MODEL;
    const size_t BLDI = BL * D_INNER;
    const int IN_W  = 2 * D_INNER * D_MODEL;        // 4.19M elems
    const int OUT_W = D_MODEL * D_INNER;            // 2.10M elems
    const int XP_W  = 96 * D_INNER;                 // 196K elems

    size_t o = 0;
    float* Pbuf  = ws + o; o += BLDM;   // also: hnb (bf16) early in layer
    float* u_raw = ws + o; o += BLDI;   // then dtb; then ucb (bf16 gate out)
    float* zb    = ws + o; o += BLDI;
    float* uc    = ws + o; o += BLDI;
    float* xdbl  = ws + o; o += BL * 96;
    float* h1    = ws + o; o += BLDM;   // also: Xpart (split-K partials)
    float* Fbuf  = ws + o; o += BLDM;
    short* ucx   = (short*)(ws + o); o += BLDI / 2;       // bf16 conv output
    short* wbuf  = (short*)(ws + o); o += (size_t)(IN_W + OUT_W + XP_W + 1) / 2;

    short* hnb = (short*)Pbuf;
    float* dtb = u_raw;
    short* ucb = (short*)u_raw;
    float* Xpart = h1;                  // h1 only needed across layer boundary

    for (int layer = 0; layer < DEPTH; ++layer) {
        const float* src = (layer == 0) ? x : h1;
        float* dst = (layer == DEPTH - 1) ? out : h1;

        layernorm_kernel<<<(int)BL, 256, 0, stream>>>(
            src, norm_w + (size_t)layer * D_MODEL, norm_b + (size_t)layer * D_MODEL, hnb);

        convert_bf16_kernel<<<IN_W / 1024, 256, 0, stream>>>(
            in_proj + (size_t)layer * IN_W, wbuf);
        convert_bf16_kernel<<<OUT_W / 1024, 256, 0, stream>>>(
            out_proj + (size_t)layer * OUT_W, wbuf + IN_W);
        convert_bf16_kernel<<<XP_W / 1024, 256, 0, stream>>>(
            x_proj + (size_t)layer * XP_W, wbuf + IN_W + OUT_W);

        gemm_bf16_kernel<<<dim3(D_INNER / 128, BL / 128), 256, 0, stream>>>(
            hnb, wbuf, u_raw, (int)BL, D_INNER, D_MODEL);
        gemm_bf16_kernel<<<dim3(D_INNER / 128, BL / 128), 256, 0, stream>>>(
            hnb, wbuf + (size_t)D_INNER * D_MODEL, zb, (int)BL, D_INNER, D_MODEL);

        conv_silu_kernel<<<(int)(BLDI / 256), 256, 0, stream>>>(
            u_raw, uc, ucx, conv_w + (size_t)layer * D_INNER * D_CONV,
            conv_b + (size_t)layer * D_INNER);

        xproj_kernel<<<dim3(XSPLITK, BL / 64), 256, 0, stream>>>(
            ucx, wbuf + IN_W + OUT_W, Xpart);
        xreduce_kernel<<<(int)(BL * 96 / 256), 256, 0, stream>>>(Xpart, xdbl);

        gemm_nt_kernel<<<dim3(D_INNER / 64, BL / 64), 256, 0, stream>>>(
            xdbl, dt_proj + (size_t)layer * D_INNER * DT_RANK, dtb,
            (int)BL, D_INNER, DT_RANK, 96,
            dt_projb + (size_t)layer * D_INNER, 1);

        const float* Al = A_log + (size_t)layer * D_INNER * D_STATE;
        scan_phase1_kernel<<<dim3(D_INNER / 256, NCHUNK, BQ), 256, 0, stream>>>(
            uc, dtb, xdbl, Al, Pbuf, Fbuf);
        scan_phase2_kernel<<<dim3(D_INNER / 256, D_STATE, BQ), 256, 0, stream>>>(
            Pbuf, Fbuf);
        scan_phase3_kernel<<<dim3(D_INNER / 256, NCHUNK, BQ), 256, 0, stream>>>(
            uc, uc, dtb, xdbl, Al, Dp + (size_t)layer * D_INNER, Fbuf);

        gate_convert_kernel<<<(int)(BLDI / 1024), 256, 0, stream>>>(uc, zb, ucb);

        gemm_bf16_kernel<<<dim3(D_MODEL / 128, BL / 128), 256, 0, stream>>>(
            ucb, wbuf + IN_W, dst, (int)BL, D_MODEL, D_INNER);
    }
}

// Round 5
// 645.618 us; speedup vs baseline: 8.8603x; 1.2424x over previous
//
#include <hip/hip_runtime.h>
#include <hip/hip_bf16.h>
#include <math.h>

#define BQ 2
#define LQ 2048
#define D_MODEL 1024
#define D_INNER 2048
#define D_STATE 16
#define DT_RANK 64
#define D_CONV 4
#define DEPTH 2
#define NCHUNK 64
#define CHUNK 32
#define XSPLITK 8
#define XKC (D_INNER / XSPLITK)   // 256

typedef __attribute__((ext_vector_type(8))) short short8v;  // 8 bf16 (4 VGPRs)
typedef __attribute__((ext_vector_type(4))) float f32x4;

__device__ __forceinline__ short f2bf(float f) {
    union { float f; unsigned u; } v; v.f = f;
    unsigned r = v.u + 0x7fffu + ((v.u >> 16) & 1u);   // RNE
    return (short)(r >> 16);
}

__device__ __forceinline__ void async16(void* lds, const void* gp) {
    __builtin_amdgcn_global_load_lds(
        (const __attribute__((address_space(1))) void*)gp,
        (__attribute__((address_space(3))) void*)lds, 16, 0, 0);
}

// ------------------------------------------------- LayerNorm (bf16 output)
__global__ __launch_bounds__(256) void layernorm_kernel(
    const float* __restrict__ x, const float* __restrict__ w,
    const float* __restrict__ b, short* __restrict__ out)
{
    __shared__ float red[8];
    int row = blockIdx.x;
    const float* xr = x + (size_t)row * D_MODEL;
    float v[4];
    float s = 0.f, sq = 0.f;
#pragma unroll
    for (int i = 0; i < 4; ++i) {
        v[i] = xr[threadIdx.x + i * 256];
        s += v[i];
        sq += v[i] * v[i];
    }
#pragma unroll
    for (int off = 32; off; off >>= 1) {
        s += __shfl_down(s, off, 64);
        sq += __shfl_down(sq, off, 64);
    }
    int wid = threadIdx.x >> 6, lane = threadIdx.x & 63;
    if (!lane) { red[wid] = s; red[4 + wid] = sq; }
    __syncthreads();
    s = red[0] + red[1] + red[2] + red[3];
    sq = red[4] + red[5] + red[6] + red[7];
    float mu = s * (1.f / D_MODEL);
    float var = sq * (1.f / D_MODEL) - mu * mu;
    float rstd = rsqrtf(var + 1e-5f);
#pragma unroll
    for (int i = 0; i < 4; ++i) {
        int c = threadIdx.x + i * 256;
        out[(size_t)row * D_MODEL + c] = f2bf((v[i] - mu) * rstd * w[c] + b[c]);
    }
}

// ------------------------------------------------ bf16 MFMA GEMM (m97 style)
__global__ __launch_bounds__(256) void gemm_bf16_kernel(
    const short* __restrict__ A, const short* __restrict__ W,
    float* __restrict__ C, int M, int N, int K)
{
    __shared__ __align__(16) short As[128 * 32];
    __shared__ __align__(16) short Bs[128 * 32];
    int tid = threadIdx.x;
    int lane = tid & 63, wv = tid >> 6;
    int bm = blockIdx.y * 128, bn = blockIdx.x * 128;
    int wr = wv >> 1, wc = wv & 1;

    f32x4 acc[4][4] = {};

    const short* Ag = A + (size_t)(bm + wv * 16 + (lane >> 2)) * K + (lane & 3) * 8;
    const short* Bg = W + (size_t)(bn + wv * 16 + (lane >> 2)) * K + (lane & 3) * 8;
    short* As0 = &As[(wv * 16) * 32];
    short* As1 = &As[(64 + wv * 16) * 32];
    short* Bs0 = &Bs[(wv * 16) * 32];
    short* Bs1 = &Bs[(64 + wv * 16) * 32];
    size_t rowskip = (size_t)64 * K;

    int fr = lane & 15, fk = (lane >> 4) * 8;

    for (int k0 = 0; k0 < K; k0 += 32) {
        async16(As0, Ag + k0);
        async16(As1, Ag + rowskip + k0);
        async16(Bs0, Bg + k0);
        async16(Bs1, Bg + rowskip + k0);
        __syncthreads();
        short8v af[4], bf[4];
#pragma unroll
        for (int i = 0; i < 4; ++i)
            af[i] = *(const short8v*)&As[(wr * 64 + i * 16 + fr) * 32 + fk];
#pragma unroll
        for (int j = 0; j < 4; ++j)
            bf[j] = *(const short8v*)&Bs[(wc * 64 + j * 16 + fr) * 32 + fk];
#pragma unroll
        for (int i = 0; i < 4; ++i)
#pragma unroll
            for (int j = 0; j < 4; ++j)
                acc[i][j] = __builtin_amdgcn_mfma_f32_16x16x32_bf16(
                    af[i], bf[j], acc[i][j], 0, 0, 0);
        __syncthreads();
    }

    int cr = (lane >> 4) * 4, cc = lane & 15;
#pragma unroll
    for (int i = 0; i < 4; ++i) {
#pragma unroll
        for (int q = 0; q < 4; ++q) {
            int row = bm + wr * 64 + i * 16 + cr + q;
            float* Cp = C + (size_t)row * N + bn + wc * 64 + cc;
#pragma unroll
            for (int j = 0; j < 4; ++j)
                Cp[j * 16] = acc[i][j][q];
        }
    }
}

// ------------------------- x_proj: tall-skinny split-K bf16 MFMA, no LDS
__global__ __launch_bounds__(256) void xproj_kernel(
    const short* __restrict__ A, const short* __restrict__ W,
    float* __restrict__ Xpart)
{
    int lane = threadIdx.x & 63, wv = threadIdx.x >> 6;
    int sk = blockIdx.x;
    int m0 = blockIdx.y * 64 + wv * 16;
    int fr = lane & 15, fk = (lane >> 4) * 8;
    const short* Ap = A + (size_t)(m0 + fr) * D_INNER + sk * XKC + fk;
    const short* Wp = W + (size_t)fr * D_INNER + sk * XKC + fk;
    f32x4 acc[6] = {};
    for (int k = 0; k < XKC; k += 32) {
        short8v af = *(const short8v*)(Ap + k);
#pragma unroll
        for (int j = 0; j < 6; ++j) {
            short8v bf = *(const short8v*)(Wp + (size_t)j * 16 * D_INNER + k);
            acc[j] = __builtin_amdgcn_mfma_f32_16x16x32_bf16(af, bf, acc[j], 0, 0, 0);
        }
    }
    int cr = (lane >> 4) * 4, cc = lane & 15;
    float* Op = Xpart + ((size_t)sk * (BQ * LQ) + m0 + cr) * 96 + cc;
#pragma unroll
    for (int j = 0; j < 6; ++j)
#pragma unroll
        for (int q = 0; q < 4; ++q)
            Op[(size_t)q * 96 + j * 16] = acc[j][q];
}

__global__ __launch_bounds__(256) void xreduce_kernel(
    const float* __restrict__ Xpart, float* __restrict__ xdbl)
{
    size_t i = (size_t)blockIdx.x * 256 + threadIdx.x;
    float s = 0.f;
#pragma unroll
    for (int sk = 0; sk < XSPLITK; ++sk)
        s += Xpart[(size_t)sk * ((size_t)BQ * LQ * 96) + i];
    xdbl[i] = s;
}

// ---------------------------------------------------------------- GEMM (f32)
__global__ __launch_bounds__(256) void gemm_nt_kernel(
    const float* __restrict__ A, const float* __restrict__ W,
    float* __restrict__ C, int M, int N, int K, int lda,
    const float* __restrict__ bias, int epilogue)
{
    __shared__ float As[16][64];
    __shared__ float Ws[16][64];
    int tid = threadIdx.x;
    int tx = tid & 15, ty = tid >> 4;
    int bm = blockIdx.y * 64;
    int bn = blockIdx.x * 64;
    int lr = tid >> 2;
    int lk = (tid & 3) * 4;
    float acc[4][4] = {};

    for (int k0 = 0; k0 < K; k0 += 16) {
        {
            const float* src = A + (size_t)(bm + lr) * lda + k0 + lk;
            float4 v = *(const float4*)src;
            As[lk + 0][lr] = v.x; As[lk + 1][lr] = v.y;
            As[lk + 2][lr] = v.z; As[lk + 3][lr] = v.w;
        }
        {
            int n = bn + lr;
            float4 v = make_float4(0.f, 0.f, 0.f, 0.f);
            if (n < N) v = *(const float4*)(W + (size_t)n * K + k0 + lk);
            Ws[lk + 0][lr] = v.x; Ws[lk + 1][lr] = v.y;
            Ws[lk + 2][lr] = v.z; Ws[lk + 3][lr] = v.w;
        }
        __syncthreads();
#pragma unroll
        for (int k = 0; k < 16; ++k) {
            float4 a = *(const float4*)&As[k][ty * 4];
            float4 w = *(const float4*)&Ws[k][tx * 4];
            float av[4] = {a.x, a.y, a.z, a.w};
            float wv[4] = {w.x, w.y, w.z, w.w};
#pragma unroll
            for (int i = 0; i < 4; ++i)
#pragma unroll
                for (int j = 0; j < 4; ++j)
                    acc[i][j] += av[i] * wv[j];
        }
        __syncthreads();
    }

#pragma unroll
    for (int i = 0; i < 4; ++i) {
        int row = bm + ty * 4 + i;
#pragma unroll
        for (int j = 0; j < 4; ++j) {
            int col = bn + tx * 4 + j;
            if (col < N) {
                float v = acc[i][j];
                if (epilogue == 1) {
                    v += bias[col];
                    v = (v > 20.f) ? v : log1pf(expf(v));
                }
                C[(size_t)row * N + col] = v;
            }
        }
    }
}

// --------------------------- causal conv + SiLU (writes f32 + bf16 copies)
__global__ __launch_bounds__(256) void conv_silu_kernel(
    const float* __restrict__ u, float* __restrict__ out,
    short* __restrict__ outb, const float* __restrict__ w,
    const float* __restrict__ bias)
{
    int idx = blockIdx.x * 256 + threadIdx.x;
    int c = idx & (D_INNER - 1);
    int bl = idx / D_INNER;
    int l = bl & (LQ - 1);
    int b = bl / LQ;
    float acc = bias[c];
#pragma unroll
    for (int k = 0; k < D_CONV; ++k) {
        int ls = l - (D_CONV - 1) + k;
        if (ls >= 0)
            acc += u[((size_t)b * LQ + ls) * D_INNER + c] * w[c * D_CONV + k];
    }
    float val = acc / (1.f + __expf(-acc));
    out[idx] = val;
    outb[idx] = f2bf(val);
}

// -------------------------------------------- selective scan, chunked 3-phase
// phase 1: LDS-staged B rows; native exp
__global__ __launch_bounds__(256) void scan_phase1_kernel(
    const float* __restrict__ u, const float* __restrict__ dt,
    const float* __restrict__ xdbl, const float* __restrict__ A_log,
    float* __restrict__ Pbuf, float* __restrict__ Fbuf)
{
    __shared__ float S[CHUNK][D_STATE];
    int t = threadIdx.x;
    int d = blockIdx.x * 256 + t;
    int c = blockIdx.y;
    int b = blockIdx.z;
    int l0 = c * CHUNK;
    {   // stage B slice: 32 rows x 16 cols
        int row = t >> 3, cc2 = (t & 7) * 2;
        const float* src = xdbl + ((size_t)(b * LQ + l0 + row)) * 96 + DT_RANK + cc2;
        *(float2*)&S[row][cc2] = *(const float2*)src;
    }
    float A[D_STATE], h[D_STATE], P[D_STATE];
    {
        const float4* ap = (const float4*)(A_log + (size_t)d * D_STATE);
#pragma unroll
        for (int g = 0; g < 4; ++g) {
            float4 a = ap[g];
            A[g*4+0] = -__expf(a.x); A[g*4+1] = -__expf(a.y);
            A[g*4+2] = -__expf(a.z); A[g*4+3] = -__expf(a.w);
        }
    }
#pragma unroll
    for (int n = 0; n < D_STATE; ++n) { h[n] = 0.f; P[n] = 1.f; }
    const float* up  = u  + ((size_t)b * LQ + l0) * D_INNER + d;
    const float* dtp = dt + ((size_t)b * LQ + l0) * D_INNER + d;
    __syncthreads();

    for (int l = 0; l < CHUNK; ++l) {
        float uv  = up[(size_t)l * D_INNER];
        float dtv = dtp[(size_t)l * D_INNER];
        float du = dtv * uv;
#pragma unroll
        for (int n4 = 0; n4 < D_STATE; n4 += 4) {
            float4 Bv = *(const float4*)&S[l][n4];
            float bb[4] = {Bv.x, Bv.y, Bv.z, Bv.w};
#pragma unroll
            for (int k = 0; k < 4; ++k) {
                int n = n4 + k;
                float dA = __expf(dtv * A[n]);
                P[n] *= dA;
                h[n] = dA * h[n] + du * bb[k];
            }
        }
    }
    size_t base = ((size_t)(b * NCHUNK + c) * D_STATE) * D_INNER + d;
#pragma unroll
    for (int n = 0; n < D_STATE; ++n) {
        Pbuf[base + (size_t)n * D_INNER] = P[n];
        Fbuf[base + (size_t)n * D_INNER] = h[n];
    }
}

__global__ __launch_bounds__(256) void scan_phase2_kernel(
    const float* __restrict__ Pbuf, float* __restrict__ Fbuf)
{
    int d = blockIdx.x * 256 + threadIdx.x;
    int n = blockIdx.y;
    int b = blockIdx.z;
    float hinit = 0.f;
    for (int c = 0; c < NCHUNK; ++c) {
        size_t idx = ((size_t)(b * NCHUNK + c) * D_STATE + n) * D_INNER + d;
        float P = Pbuf[idx];
        float F = Fbuf[idx];
        Fbuf[idx] = hinit;
        hinit = P * hinit + F;
    }
}

// phase 3: LDS-staged B+C (XOR-swizzled), native exp, fused silu(z) gate,
// writes bf16 directly for out_proj.
__global__ __launch_bounds__(256) void scan_phase3_kernel(
    const float* __restrict__ u, const float* __restrict__ dt,
    const float* __restrict__ xdbl, const float* __restrict__ A_log,
    const float* __restrict__ Dp, const float* __restrict__ Hinit,
    const float* __restrict__ z, short* __restrict__ yout)
{
    __shared__ float S[CHUNK][32];
    int t = threadIdx.x;
    int d = blockIdx.x * 256 + t;
    int c = blockIdx.y;
    int b = blockIdx.z;
    int l0 = c * CHUNK;
    {   // stage B+C slice: 32 rows x 32 cols, XOR-swizzle for conflict-free b128 write
        int row = t >> 3, cg = (t & 7) * 4;
        const float* src = xdbl + ((size_t)(b * LQ + l0 + row)) * 96 + DT_RANK + cg;
        *(float4*)&S[row][cg ^ ((row & 7) << 2)] = *(const float4*)src;
    }
    float A[D_STATE], h[D_STATE];
    {
        const float4* ap = (const float4*)(A_log + (size_t)d * D_STATE);
#pragma unroll
        for (int g = 0; g < 4; ++g) {
            float4 a = ap[g];
            A[g*4+0] = -__expf(a.x); A[g*4+1] = -__expf(a.y);
            A[g*4+2] = -__expf(a.z); A[g*4+3] = -__expf(a.w);
        }
    }
    size_t base = ((size_t)(b * NCHUNK + c) * D_STATE) * D_INNER + d;
#pragma unroll
    for (int n = 0; n < D_STATE; ++n)
        h[n] = Hinit[base + (size_t)n * D_INNER];
    float Dd = Dp[d];
    const float* up  = u  + ((size_t)b * LQ + l0) * D_INNER + d;
    const float* dtp = dt + ((size_t)b * LQ + l0) * D_INNER + d;
    const float* zp  = z  + ((size_t)b * LQ + l0) * D_INNER + d;
    short* yp = yout + ((size_t)b * LQ + l0) * D_INNER + d;
    __syncthreads();

    for (int l = 0; l < CHUNK; ++l) {
        float uv  = up[(size_t)l * D_INNER];
        float dtv = dtp[(size_t)l * D_INNER];
        float du = dtv * uv;
        float acc = 0.f;
        int sw = (l & 7) << 2;
#pragma unroll
        for (int n4 = 0; n4 < D_STATE; n4 += 4) {
            float4 Bv = *(const float4*)&S[l][n4 ^ sw];
            float4 Cv = *(const float4*)&S[l][(16 + n4) ^ sw];
            float bb[4] = {Bv.x, Bv.y, Bv.z, Bv.w};
            float cc[4] = {Cv.x, Cv.y, Cv.z, Cv.w};
#pragma unroll
            for (int k = 0; k < 4; ++k) {
                int n = n4 + k;
                float dA = __expf(dtv * A[n]);
                h[n] = dA * h[n] + du * bb[k];
                acc += h[n] * cc[k];
            }
        }
        float y = acc + uv * Dd;
        float zv = zp[(size_t)l * D_INNER];
        float g = zv / (1.f + __expf(-zv));
        yp[(size_t)l * D_INNER] = f2bf(y * g);
    }
}

// --------------------------------------------------- f32 -> bf16 conversion
__global__ __launch_bounds__(256) void convert_bf16_kernel(
    const float* __restrict__ in, short* __restrict__ out)
{
    int i = (blockIdx.x * 256 + threadIdx.x) * 4;
    float4 v = *(const float4*)(in + i);
    short4 o = make_short4(f2bf(v.x), f2bf(v.y), f2bf(v.z), f2bf(v.w));
    *(short4*)(out + i) = o;
}

// ---------------------------------------------------------------- launcher
extern "C" void kernel_launch(void* const* d_in, const int* in_sizes, int n_in,
                              void* d_out, int out_size, void* d_ws, size_t ws_size,
                              hipStream_t stream)
{
    const float* x        = (const float*)d_in[0];
    const float* norm_w   = (const float*)d_in[2];
    const float* norm_b   = (const float*)d_in[3];
    const float* in_proj  = (const float*)d_in[4];
    const float* conv_w   = (const float*)d_in[5];
    const float* conv_b   = (const float*)d_in[6];
    const float* x_proj   = (const float*)d_in[7];
    const float* dt_proj  = (const float*)d_in[8];
    const float* dt_projb = (const float*)d_in[9];
    const float* A_log    = (const float*)d_in[10];
    const float* Dp       = (const float*)d_in[11];
    const float* out_proj = (const float*)d_in[12];
    float* out = (float*)d_out;
    float* ws  = (float*)d_ws;

    const size_t BL   = (size_t)BQ * LQ;            // 4096
    const size_t BLDM = BL * D_MODEL;
    const size_t BLDI = BL * D_INNER;
    const int IN_W  = 2 * D_INNER * D_MODEL;
    const int OUT_W = D_MODEL * D_INNER;
    const int XP_W  = 96 * D_INNER;

    size_t o = 0;
    float* Pbuf  = ws + o; o += BLDM;   // also: hnb (bf16) early in layer
    float* u_raw = ws + o; o += BLDI;   // then dtb
    float* zb    = ws + o; o += BLDI;
    float* uc    = ws + o; o += BLDI;
    float* xdbl  = ws + o; o += BL * 96;
    float* h1    = ws + o; o += BLDM;   // also: Xpart (split-K partials)
    float* Fbuf  = ws + o; o += BLDM;
    short* ucx   = (short*)(ws + o); o += BLDI / 2;  // conv bf16 out; then gated bf16 y
    short* wbuf  = (short*)(ws + o); o += (size_t)(IN_W + OUT_W + XP_W + 1) / 2;

    short* hnb = (short*)Pbuf;
    float* dtb = u_raw;
    float* Xpart = h1;

    for (int layer = 0; layer < DEPTH; ++layer) {
        const float* src = (layer == 0) ? x : h1;
        float* dst = (layer == DEPTH - 1) ? out : h1;

        layernorm_kernel<<<(int)BL, 256, 0, stream>>>(
            src, norm_w + (size_t)layer * D_MODEL, norm_b + (size_t)layer * D_MODEL, hnb);

        convert_bf16_kernel<<<IN_W / 1024, 256, 0, stream>>>(
            in_proj + (size_t)layer * IN_W, wbuf);
        convert_bf16_kernel<<<OUT_W / 1024, 256, 0, stream>>>(
            out_proj + (size_t)layer * OUT_W, wbuf + IN_W);
        convert_bf16_kernel<<<XP_W / 1024, 256, 0, stream>>>(
            x_proj + (size_t)layer * XP_W, wbuf + IN_W + OUT_W);

        gemm_bf16_kernel<<<dim3(D_INNER / 128, BL / 128), 256, 0, stream>>>(
            hnb, wbuf, u_raw, (int)BL, D_INNER, D_MODEL);
        gemm_bf16_kernel<<<dim3(D_INNER / 128, BL / 128), 256, 0, stream>>>(
            hnb, wbuf + (size_t)D_INNER * D_MODEL, zb, (int)BL, D_INNER, D_MODEL);

        conv_silu_kernel<<<(int)(BLDI / 256), 256, 0, stream>>>(
            u_raw, uc, ucx, conv_w + (size_t)layer * D_INNER * D_CONV,
            conv_b + (size_t)layer * D_INNER);

        xproj_kernel<<<dim3(XSPLITK, BL / 64), 256, 0, stream>>>(
            ucx, wbuf + IN_W + OUT_W, Xpart);
        xreduce_kernel<<<(int)(BL * 96 / 256), 256, 0, stream>>>(Xpart, xdbl);

        gemm_nt_kernel<<<dim3(D_INNER / 64, BL / 64), 256, 0, stream>>>(
            xdbl, dt_proj + (size_t)layer * D_INNER * DT_RANK, dtb,
            (int)BL, D_INNER, DT_RANK, 96,
            dt_projb + (size_t)layer * D_INNER, 1);

        const float* Al = A_log + (size_t)layer * D_INNER * D_STATE;
        scan_phase1_kernel<<<dim3(D_INNER / 256, NCHUNK, BQ), 256, 0, stream>>>(
            uc, dtb, xdbl, Al, Pbuf, Fbuf);
        scan_phase2_kernel<<<dim3(D_INNER / 256, D_STATE, BQ), 256, 0, stream>>>(
            Pbuf, Fbuf);
        scan_phase3_kernel<<<dim3(D_INNER / 256, NCHUNK, BQ), 256, 0, stream>>>(
            uc, dtb, xdbl, Al, Dp + (size_t)layer * D_INNER, Fbuf, zb, ucx);

        gemm_bf16_kernel<<<dim3(D_MODEL / 128, BL / 128), 256, 0, stream>>>(
            ucx, wbuf + IN_W, dst, (int)BL, D_MODEL, D_INNER);
    }
}

// Round 6
// 597.730 us; speedup vs baseline: 9.5701x; 1.0801x over previous
//
#include <hip/hip_runtime.h>
#include <hip/hip_bf16.h>
#include <math.h>

#define BQ 2
#define LQ 2048
#define D_MODEL 1024
#define D_INNER 2048
#define D_STATE 16
#define DT_RANK 64
#define D_CONV 4
#define DEPTH 2
#define NCHUNK 64
#define CHUNK 32
#define XSPLITK 8
#define XKC (D_INNER / XSPLITK)   // 256

typedef __attribute__((ext_vector_type(8))) short short8v;  // 8 bf16 (4 VGPRs)
typedef __attribute__((ext_vector_type(4))) float f32x4;

__device__ __forceinline__ short f2bf(float f) {
    union { float f; unsigned u; } v; v.f = f;
    unsigned r = v.u + 0x7fffu + ((v.u >> 16) & 1u);   // RNE
    return (short)(r >> 16);
}

__device__ __forceinline__ float bf2f(unsigned short s) {
    union { unsigned u; float f; } v; v.u = ((unsigned)s) << 16;
    return v.f;
}

__device__ __forceinline__ void async16(void* lds, const void* gp) {
    __builtin_amdgcn_global_load_lds(
        (const __attribute__((address_space(1))) void*)gp,
        (__attribute__((address_space(3))) void*)lds, 16, 0, 0);
}

// ------------------------------------------------- LayerNorm (bf16 output)
__global__ __launch_bounds__(256) void layernorm_kernel(
    const float* __restrict__ x, const float* __restrict__ w,
    const float* __restrict__ b, short* __restrict__ out)
{
    __shared__ float red[8];
    int row = blockIdx.x;
    const float* xr = x + (size_t)row * D_MODEL;
    float v[4];
    float s = 0.f, sq = 0.f;
#pragma unroll
    for (int i = 0; i < 4; ++i) {
        v[i] = xr[threadIdx.x + i * 256];
        s += v[i];
        sq += v[i] * v[i];
    }
#pragma unroll
    for (int off = 32; off; off >>= 1) {
        s += __shfl_down(s, off, 64);
        sq += __shfl_down(sq, off, 64);
    }
    int wid = threadIdx.x >> 6, lane = threadIdx.x & 63;
    if (!lane) { red[wid] = s; red[4 + wid] = sq; }
    __syncthreads();
    s = red[0] + red[1] + red[2] + red[3];
    sq = red[4] + red[5] + red[6] + red[7];
    float mu = s * (1.f / D_MODEL);
    float var = sq * (1.f / D_MODEL) - mu * mu;
    float rstd = rsqrtf(var + 1e-5f);
#pragma unroll
    for (int i = 0; i < 4; ++i) {
        int c = threadIdx.x + i * 256;
        out[(size_t)row * D_MODEL + c] = f2bf((v[i] - mu) * rstd * w[c] + b[c]);
    }
}

// ------------------------------------------------ bf16 MFMA GEMM (m97 style)
// epilogue 0: plain; 1: softplus(acc + bias[col])
__global__ __launch_bounds__(256) void gemm_bf16_kernel(
    const short* __restrict__ A, const short* __restrict__ W,
    float* __restrict__ C, int M, int N, int K,
    const float* __restrict__ bias, int epilogue)
{
    __shared__ __align__(16) short As[128 * 32];
    __shared__ __align__(16) short Bs[128 * 32];
    int tid = threadIdx.x;
    int lane = tid & 63, wv = tid >> 6;
    int bm = blockIdx.y * 128, bn = blockIdx.x * 128;
    int wr = wv >> 1, wc = wv & 1;

    f32x4 acc[4][4] = {};

    const short* Ag = A + (size_t)(bm + wv * 16 + (lane >> 2)) * K + (lane & 3) * 8;
    const short* Bg = W + (size_t)(bn + wv * 16 + (lane >> 2)) * K + (lane & 3) * 8;
    short* As0 = &As[(wv * 16) * 32];
    short* As1 = &As[(64 + wv * 16) * 32];
    short* Bs0 = &Bs[(wv * 16) * 32];
    short* Bs1 = &Bs[(64 + wv * 16) * 32];
    size_t rowskip = (size_t)64 * K;

    int fr = lane & 15, fk = (lane >> 4) * 8;

    for (int k0 = 0; k0 < K; k0 += 32) {
        async16(As0, Ag + k0);
        async16(As1, Ag + rowskip + k0);
        async16(Bs0, Bg + k0);
        async16(Bs1, Bg + rowskip + k0);
        __syncthreads();
        short8v af[4], bf[4];
#pragma unroll
        for (int i = 0; i < 4; ++i)
            af[i] = *(const short8v*)&As[(wr * 64 + i * 16 + fr) * 32 + fk];
#pragma unroll
        for (int j = 0; j < 4; ++j)
            bf[j] = *(const short8v*)&Bs[(wc * 64 + j * 16 + fr) * 32 + fk];
#pragma unroll
        for (int i = 0; i < 4; ++i)
#pragma unroll
            for (int j = 0; j < 4; ++j)
                acc[i][j] = __builtin_amdgcn_mfma_f32_16x16x32_bf16(
                    af[i], bf[j], acc[i][j], 0, 0, 0);
        __syncthreads();
    }

    int cr = (lane >> 4) * 4, cc = lane & 15;
#pragma unroll
    for (int i = 0; i < 4; ++i) {
#pragma unroll
        for (int q = 0; q < 4; ++q) {
            int row = bm + wr * 64 + i * 16 + cr + q;
            float* Cp = C + (size_t)row * N + bn + wc * 64 + cc;
#pragma unroll
            for (int j = 0; j < 4; ++j) {
                float v = acc[i][j][q];
                if (epilogue == 1) {
                    v += bias[bn + wc * 64 + cc + j * 16];
                    v = (v > 20.f) ? v : __logf(1.f + __expf(v));
                }
                Cp[j * 16] = v;
            }
        }
    }
}

// ------------------------- x_proj: tall-skinny split-K bf16 MFMA, no LDS
__global__ __launch_bounds__(256) void xproj_kernel(
    const short* __restrict__ A, const short* __restrict__ W,
    float* __restrict__ Xpart)
{
    int lane = threadIdx.x & 63, wv = threadIdx.x >> 6;
    int sk = blockIdx.x;
    int m0 = blockIdx.y * 64 + wv * 16;
    int fr = lane & 15, fk = (lane >> 4) * 8;
    const short* Ap = A + (size_t)(m0 + fr) * D_INNER + sk * XKC + fk;
    const short* Wp = W + (size_t)fr * D_INNER + sk * XKC + fk;
    f32x4 acc[6] = {};
    for (int k = 0; k < XKC; k += 32) {
        short8v af = *(const short8v*)(Ap + k);
#pragma unroll
        for (int j = 0; j < 6; ++j) {
            short8v bf = *(const short8v*)(Wp + (size_t)j * 16 * D_INNER + k);
            acc[j] = __builtin_amdgcn_mfma_f32_16x16x32_bf16(af, bf, acc[j], 0, 0, 0);
        }
    }
    int cr = (lane >> 4) * 4, cc = lane & 15;
    float* Op = Xpart + ((size_t)sk * (BQ * LQ) + m0 + cr) * 96 + cc;
#pragma unroll
    for (int j = 0; j < 6; ++j)
#pragma unroll
        for (int q = 0; q < 4; ++q)
            Op[(size_t)q * 96 + j * 16] = acc[j][q];
}

// reduce split-K partials -> xdbl f32; also emit compact bf16 dt_r [BL][64]
__global__ __launch_bounds__(256) void xreduce_kernel(
    const float* __restrict__ Xpart, float* __restrict__ xdbl,
    short* __restrict__ dtr)
{
    size_t i = (size_t)blockIdx.x * 256 + threadIdx.x;
    float s = 0.f;
#pragma unroll
    for (int sk = 0; sk < XSPLITK; ++sk)
        s += Xpart[(size_t)sk * ((size_t)BQ * LQ * 96) + i];
    xdbl[i] = s;
    int col = (int)(i % 96);
    if (col < DT_RANK)
        dtr[(i / 96) * DT_RANK + col] = f2bf(s);
}

// --------------------------- causal conv + SiLU (bf16 output only)
__global__ __launch_bounds__(256) void conv_silu_kernel(
    const float* __restrict__ u, short* __restrict__ outb,
    const float* __restrict__ w, const float* __restrict__ bias)
{
    int idx = blockIdx.x * 256 + threadIdx.x;
    int c = idx & (D_INNER - 1);
    int bl = idx / D_INNER;
    int l = bl & (LQ - 1);
    int b = bl / LQ;
    float acc = bias[c];
#pragma unroll
    for (int k = 0; k < D_CONV; ++k) {
        int ls = l - (D_CONV - 1) + k;
        if (ls >= 0)
            acc += u[((size_t)b * LQ + ls) * D_INNER + c] * w[c * D_CONV + k];
    }
    float val = acc / (1.f + __expf(-acc));
    outb[idx] = f2bf(val);
}

// -------------------------------------------- selective scan, chunked 3-phase
__global__ __launch_bounds__(256) void scan_phase1_kernel(
    const unsigned short* __restrict__ u, const float* __restrict__ dt,
    const float* __restrict__ xdbl, const float* __restrict__ A_log,
    float* __restrict__ Pbuf, float* __restrict__ Fbuf)
{
    __shared__ float S[CHUNK][D_STATE];
    int t = threadIdx.x;
    int d = blockIdx.x * 256 + t;
    int c = blockIdx.y;
    int b = blockIdx.z;
    int l0 = c * CHUNK;
    {   // stage B slice: 32 rows x 16 cols
        int row = t >> 3, cc2 = (t & 7) * 2;
        const float* src = xdbl + ((size_t)(b * LQ + l0 + row)) * 96 + DT_RANK + cc2;
        *(float2*)&S[row][cc2] = *(const float2*)src;
    }
    float A[D_STATE], h[D_STATE], P[D_STATE];
    {
        const float4* ap = (const float4*)(A_log + (size_t)d * D_STATE);
#pragma unroll
        for (int g = 0; g < 4; ++g) {
            float4 a = ap[g];
            A[g*4+0] = -__expf(a.x); A[g*4+1] = -__expf(a.y);
            A[g*4+2] = -__expf(a.z); A[g*4+3] = -__expf(a.w);
        }
    }
#pragma unroll
    for (int n = 0; n < D_STATE; ++n) { h[n] = 0.f; P[n] = 1.f; }
    const unsigned short* up = u + ((size_t)b * LQ + l0) * D_INNER + d;
    const float* dtp = dt + ((size_t)b * LQ + l0) * D_INNER + d;
    __syncthreads();

    for (int l = 0; l < CHUNK; ++l) {
        float uv  = bf2f(up[(size_t)l * D_INNER]);
        float dtv = dtp[(size_t)l * D_INNER];
        float du = dtv * uv;
#pragma unroll
        for (int n4 = 0; n4 < D_STATE; n4 += 4) {
            float4 Bv = *(const float4*)&S[l][n4];
            float bb[4] = {Bv.x, Bv.y, Bv.z, Bv.w};
#pragma unroll
            for (int k = 0; k < 4; ++k) {
                int n = n4 + k;
                float dA = __expf(dtv * A[n]);
                P[n] *= dA;
                h[n] = dA * h[n] + du * bb[k];
            }
        }
    }
    size_t base = ((size_t)(b * NCHUNK + c) * D_STATE) * D_INNER + d;
#pragma unroll
    for (int n = 0; n < D_STATE; ++n) {
        Pbuf[base + (size_t)n * D_INNER] = P[n];
        Fbuf[base + (size_t)n * D_INNER] = h[n];
    }
}

__global__ __launch_bounds__(256) void scan_phase2_kernel(
    const float* __restrict__ Pbuf, float* __restrict__ Fbuf)
{
    int d = blockIdx.x * 256 + threadIdx.x;
    int n = blockIdx.y;
    int b = blockIdx.z;
    float hinit = 0.f;
    for (int c = 0; c < NCHUNK; ++c) {
        size_t idx = ((size_t)(b * NCHUNK + c) * D_STATE + n) * D_INNER + d;
        float P = Pbuf[idx];
        float F = Fbuf[idx];
        Fbuf[idx] = hinit;
        hinit = P * hinit + F;
    }
}

// phase 3: LDS-staged B+C (XOR-swizzled), native exp, fused silu(z) gate,
// bf16 output for out_proj.
__global__ __launch_bounds__(256) void scan_phase3_kernel(
    const unsigned short* __restrict__ u, const float* __restrict__ dt,
    const float* __restrict__ xdbl, const float* __restrict__ A_log,
    const float* __restrict__ Dp, const float* __restrict__ Hinit,
    const float* __restrict__ z, short* __restrict__ yout)
{
    __shared__ float S[CHUNK][32];
    int t = threadIdx.x;
    int d = blockIdx.x * 256 + t;
    int c = blockIdx.y;
    int b = blockIdx.z;
    int l0 = c * CHUNK;
    {   // stage B+C slice: 32 rows x 32 cols, XOR-swizzled
        int row = t >> 3, cg = (t & 7) * 4;
        const float* src = xdbl + ((size_t)(b * LQ + l0 + row)) * 96 + DT_RANK + cg;
        *(float4*)&S[row][cg ^ ((row & 7) << 2)] = *(const float4*)src;
    }
    float A[D_STATE], h[D_STATE];
    {
        const float4* ap = (const float4*)(A_log + (size_t)d * D_STATE);
#pragma unroll
        for (int g = 0; g < 4; ++g) {
            float4 a = ap[g];
            A[g*4+0] = -__expf(a.x); A[g*4+1] = -__expf(a.y);
            A[g*4+2] = -__expf(a.z); A[g*4+3] = -__expf(a.w);
        }
    }
    size_t base = ((size_t)(b * NCHUNK + c) * D_STATE) * D_INNER + d;
#pragma unroll
    for (int n = 0; n < D_STATE; ++n)
        h[n] = Hinit[base + (size_t)n * D_INNER];
    float Dd = Dp[d];
    const unsigned short* up = u + ((size_t)b * LQ + l0) * D_INNER + d;
    const float* dtp = dt + ((size_t)b * LQ + l0) * D_INNER + d;
    const float* zp  = z  + ((size_t)b * LQ + l0) * D_INNER + d;
    short* yp = yout + ((size_t)b * LQ + l0) * D_INNER + d;
    __syncthreads();

    for (int l = 0; l < CHUNK; ++l) {
        float uv  = bf2f(up[(size_t)l * D_INNER]);
        float dtv = dtp[(size_t)l * D_INNER];
        float du = dtv * uv;
        float acc = 0.f;
        int sw = (l & 7) << 2;
#pragma unroll
        for (int n4 = 0; n4 < D_STATE; n4 += 4) {
            float4 Bv = *(const float4*)&S[l][n4 ^ sw];
            float4 Cv = *(const float4*)&S[l][(16 + n4) ^ sw];
            float bb[4] = {Bv.x, Bv.y, Bv.z, Bv.w};
            float cc[4] = {Cv.x, Cv.y, Cv.z, Cv.w};
#pragma unroll
            for (int k = 0; k < 4; ++k) {
                int n = n4 + k;
                float dA = __expf(dtv * A[n]);
                h[n] = dA * h[n] + du * bb[k];
                acc += h[n] * cc[k];
            }
        }
        float y = acc + uv * Dd;
        float zv = zp[(size_t)l * D_INNER];
        float g = zv / (1.f + __expf(-zv));
        yp[(size_t)l * D_INNER] = f2bf(y * g);
    }
}

// --------------------------------------------------- f32 -> bf16 conversion
__global__ __launch_bounds__(256) void convert_bf16_kernel(
    const float* __restrict__ in, short* __restrict__ out)
{
    int i = (blockIdx.x * 256 + threadIdx.x) * 4;
    float4 v = *(const float4*)(in + i);
    short4 o = make_short4(f2bf(v.x), f2bf(v.y), f2bf(v.z), f2bf(v.w));
    *(short4*)(out + i) = o;
}

// ---------------------------------------------------------------- launcher
extern "C" void kernel_launch(void* const* d_in, const int* in_sizes, int n_in,
                              void* d_out, int out_size, void* d_ws, size_t ws_size,
                              hipStream_t stream)
{
    const float* x        = (const float*)d_in[0];
    const float* norm_w   = (const float*)d_in[2];
    const float* norm_b   = (const float*)d_in[3];
    const float* in_proj  = (const float*)d_in[4];
    const float* conv_w   = (const float*)d_in[5];
    const float* conv_b   = (const float*)d_in[6];
    const float* x_proj   = (const float*)d_in[7];
    const float* dt_proj  = (const float*)d_in[8];
    const float* dt_projb = (const float*)d_in[9];
    const float* A_log    = (const float*)d_in[10];
    const float* Dp       = (const float*)d_in[11];
    const float* out_proj = (const float*)d_in[12];
    float* out = (float*)d_out;
    float* ws  = (float*)d_ws;

    const size_t BL   = (size_t)BQ * LQ;            // 4096
    const size_t BLDM = BL * D_MODEL;
    const size_t BLDI = BL * D_INNER;
    const int IN_W  = 2 * D_INNER * D_MODEL;
    const int OUT_W = D_MODEL * D_INNER;
    const int XP_W  = 96 * D_INNER;
    const int DT_W  = D_INNER * DT_RANK;

    size_t o = 0;
    float* Pbuf  = ws + o; o += BLDM;   // also: hnb (bf16) early in layer
    float* u_raw = ws + o; o += BLDI;   // then dtb (f32 dt)
    float* zb    = ws + o; o += BLDI;
    float* xdbl  = ws + o; o += BL * 96;
    float* h1    = ws + o; o += BLDM;   // also: Xpart (split-K partials)
    float* Fbuf  = ws + o; o += BLDM;
    short* ucx   = (short*)(ws + o); o += BLDI / 2;  // bf16 u; then gated bf16 y
    short* dtr   = (short*)(ws + o); o += BL * DT_RANK / 2;   // bf16 dt_r
    short* wbuf  = (short*)(ws + o);
    o += (size_t)(IN_W + OUT_W + XP_W + DT_W + 1) / 2;

    short* hnb = (short*)Pbuf;
    float* dtb = u_raw;
    float* Xpart = h1;

    for (int layer = 0; layer < DEPTH; ++layer) {
        const float* src = (layer == 0) ? x : h1;
        float* dst = (layer == DEPTH - 1) ? out : h1;

        layernorm_kernel<<<(int)BL, 256, 0, stream>>>(
            src, norm_w + (size_t)layer * D_MODEL, norm_b + (size_t)layer * D_MODEL, hnb);

        convert_bf16_kernel<<<IN_W / 1024, 256, 0, stream>>>(
            in_proj + (size_t)layer * IN_W, wbuf);
        convert_bf16_kernel<<<OUT_W / 1024, 256, 0, stream>>>(
            out_proj + (size_t)layer * OUT_W, wbuf + IN_W);
        convert_bf16_kernel<<<XP_W / 1024, 256, 0, stream>>>(
            x_proj + (size_t)layer * XP_W, wbuf + IN_W + OUT_W);
        convert_bf16_kernel<<<DT_W / 1024, 256, 0, stream>>>(
            dt_proj + (size_t)layer * DT_W, wbuf + IN_W + OUT_W + XP_W);

        gemm_bf16_kernel<<<dim3(D_INNER / 128, BL / 128), 256, 0, stream>>>(
            hnb, wbuf, u_raw, (int)BL, D_INNER, D_MODEL, nullptr, 0);
        gemm_bf16_kernel<<<dim3(D_INNER / 128, BL / 128), 256, 0, stream>>>(
            hnb, wbuf + (size_t)D_INNER * D_MODEL, zb, (int)BL, D_INNER, D_MODEL,
            nullptr, 0);

        conv_silu_kernel<<<(int)(BLDI / 256), 256, 0, stream>>>(
            u_raw, ucx, conv_w + (size_t)layer * D_INNER * D_CONV,
            conv_b + (size_t)layer * D_INNER);

        xproj_kernel<<<dim3(XSPLITK, BL / 64), 256, 0, stream>>>(
            ucx, wbuf + IN_W + OUT_W, Xpart);
        xreduce_kernel<<<(int)(BL * 96 / 256), 256, 0, stream>>>(Xpart, xdbl, dtr);

        gemm_bf16_kernel<<<dim3(D_INNER / 128, BL / 128), 256, 0, stream>>>(
            dtr, wbuf + IN_W + OUT_W + XP_W, dtb, (int)BL, D_INNER, DT_RANK,
            dt_projb + (size_t)layer * D_INNER, 1);

        const float* Al = A_log + (size_t)layer * D_INNER * D_STATE;
        scan_phase1_kernel<<<dim3(D_INNER / 256, NCHUNK, BQ), 256, 0, stream>>>(
            (const unsigned short*)ucx, dtb, xdbl, Al, Pbuf, Fbuf);
        scan_phase2_kernel<<<dim3(D_INNER / 256, D_STATE, BQ), 256, 0, stream>>>(
            Pbuf, Fbuf);
        scan_phase3_kernel<<<dim3(D_INNER / 256, NCHUNK, BQ), 256, 0, stream>>>(
            (const unsigned short*)ucx, dtb, xdbl, Al,
            Dp + (size_t)layer * D_INNER, Fbuf, zb, (short*)ucx);

        gemm_bf16_kernel<<<dim3(D_MODEL / 128, BL / 128), 256, 0, stream>>>(
            ucx, wbuf + IN_W, dst, (int)BL, D_MODEL, D_INNER, nullptr, 0);
    }
}

// Round 7
// 546.242 us; speedup vs baseline: 10.4722x; 1.0943x over previous
//
#include <hip/hip_runtime.h>
#include <hip/hip_bf16.h>
#include <math.h>

#define BQ 2
#define LQ 2048
#define D_MODEL 1024
#define D_INNER 2048
#define D_STATE 16
#define DT_RANK 64
#define D_CONV 4
#define DEPTH 2
#define NCHUNK 64
#define CHUNK 32
#define XSPLITK 8
#define XKC (D_INNER / XSPLITK)   // 256

typedef __attribute__((ext_vector_type(8))) short short8v;  // 8 bf16 (4 VGPRs)
typedef __attribute__((ext_vector_type(4))) float f32x4;

__device__ __forceinline__ short f2bf(float f) {
    union { float f; unsigned u; } v; v.f = f;
    unsigned r = v.u + 0x7fffu + ((v.u >> 16) & 1u);   // RNE
    return (short)(r >> 16);
}

__device__ __forceinline__ float bf2f(unsigned short s) {
    union { unsigned u; float f; } v; v.u = ((unsigned)s) << 16;
    return v.f;
}

__device__ __forceinline__ void async16(void* lds, const void* gp) {
    __builtin_amdgcn_global_load_lds(
        (const __attribute__((address_space(1))) void*)gp,
        (__attribute__((address_space(3))) void*)lds, 16, 0, 0);
}

// ------------------------------------------------- LayerNorm (bf16 output)
__global__ __launch_bounds__(256) void layernorm_kernel(
    const float* __restrict__ x, const float* __restrict__ w,
    const float* __restrict__ b, short* __restrict__ out)
{
    __shared__ float red[8];
    int row = blockIdx.x;
    const float* xr = x + (size_t)row * D_MODEL;
    float v[4];
    float s = 0.f, sq = 0.f;
#pragma unroll
    for (int i = 0; i < 4; ++i) {
        v[i] = xr[threadIdx.x + i * 256];
        s += v[i];
        sq += v[i] * v[i];
    }
#pragma unroll
    for (int off = 32; off; off >>= 1) {
        s += __shfl_down(s, off, 64);
        sq += __shfl_down(sq, off, 64);
    }
    int wid = threadIdx.x >> 6, lane = threadIdx.x & 63;
    if (!lane) { red[wid] = s; red[4 + wid] = sq; }
    __syncthreads();
    s = red[0] + red[1] + red[2] + red[3];
    sq = red[4] + red[5] + red[6] + red[7];
    float mu = s * (1.f / D_MODEL);
    float var = sq * (1.f / D_MODEL) - mu * mu;
    float rstd = rsqrtf(var + 1e-5f);
#pragma unroll
    for (int i = 0; i < 4; ++i) {
        int c = threadIdx.x + i * 256;
        out[(size_t)row * D_MODEL + c] = f2bf((v[i] - mu) * rstd * w[c] + b[c]);
    }
}

// ---------------- bf16 MFMA GEMM: dbuf stage-early + XCD swizzle
// epilogue 0: f32 store; 1: softplus(acc+bias[col]) f32; 2: bf16 store
__global__ __launch_bounds__(256) void gemm_bf16_kernel(
    const short* __restrict__ A, const short* __restrict__ W,
    void* __restrict__ Cv, int M, int N, int K,
    const float* __restrict__ bias, int epilogue)
{
    __shared__ __align__(16) short As[2][128 * 32];
    __shared__ __align__(16) short Bs[2][128 * 32];
    int tid = threadIdx.x;
    int lane = tid & 63, wv = tid >> 6;
    int nbx = N >> 7;
    int nwg = (M >> 7) * nbx;
    int q = nwg >> 3;                       // nwg % 8 == 0 for all our shapes
    int wg = ((int)blockIdx.x & 7) * q + ((int)blockIdx.x >> 3);
    int bx = wg % nbx, by = wg / nbx;
    int bm = by * 128, bn = bx * 128;
    int wr = wv >> 1, wc = wv & 1;

    f32x4 acc[4][4] = {};

    const short* Ag = A + (size_t)(bm + wv * 16 + (lane >> 2)) * K + (lane & 3) * 8;
    const short* Bg = W + (size_t)(bn + wv * 16 + (lane >> 2)) * K + (lane & 3) * 8;
    size_t rowskip = (size_t)64 * K;
    int lo = (wv * 16) * 32;                // wave's LDS staging base (elems)

    int fr = lane & 15, fk = (lane >> 4) * 8;
    int NT = K >> 5;

    // prologue: stage tile 0 into buf 0
    async16(&As[0][lo], Ag);
    async16(&As[0][lo + 64 * 32], Ag + rowskip);
    async16(&Bs[0][lo], Bg);
    async16(&Bs[0][lo + 64 * 32], Bg + rowskip);
    __syncthreads();

    int cur = 0;
    for (int t = 0; t < NT; ++t) {
        if (t + 1 < NT) {                   // stage next tile before compute
            int k0 = (t + 1) << 5;
            int nb = cur ^ 1;
            async16(&As[nb][lo], Ag + k0);
            async16(&As[nb][lo + 64 * 32], Ag + rowskip + k0);
            async16(&Bs[nb][lo], Bg + k0);
            async16(&Bs[nb][lo + 64 * 32], Bg + rowskip + k0);
        }
        short8v af[4], bf[4];
#pragma unroll
        for (int i = 0; i < 4; ++i)
            af[i] = *(const short8v*)&As[cur][(wr * 64 + i * 16 + fr) * 32 + fk];
#pragma unroll
        for (int j = 0; j < 4; ++j)
            bf[j] = *(const short8v*)&Bs[cur][(wc * 64 + j * 16 + fr) * 32 + fk];
#pragma unroll
        for (int i = 0; i < 4; ++i)
#pragma unroll
            for (int j = 0; j < 4; ++j)
                acc[i][j] = __builtin_amdgcn_mfma_f32_16x16x32_bf16(
                    af[i], bf[j], acc[i][j], 0, 0, 0);
        __syncthreads();                    // drains next stage + frees buf[cur]
        cur ^= 1;
    }

    int cr = (lane >> 4) * 4, cc = lane & 15;
    if (epilogue == 2) {
        short* C = (short*)Cv;
#pragma unroll
        for (int i = 0; i < 4; ++i)
#pragma unroll
            for (int p = 0; p < 4; ++p) {
                int row = bm + wr * 64 + i * 16 + cr + p;
                short* Cp = C + (size_t)row * N + bn + wc * 64 + cc;
#pragma unroll
                for (int j = 0; j < 4; ++j)
                    Cp[j * 16] = f2bf(acc[i][j][p]);
            }
    } else if (epilogue == 1) {
        float* C = (float*)Cv;
#pragma unroll
        for (int i = 0; i < 4; ++i)
#pragma unroll
            for (int p = 0; p < 4; ++p) {
                int row = bm + wr * 64 + i * 16 + cr + p;
                float* Cp = C + (size_t)row * N + bn + wc * 64 + cc;
#pragma unroll
                for (int j = 0; j < 4; ++j) {
                    float v = acc[i][j][p] + bias[bn + wc * 64 + cc + j * 16];
                    Cp[j * 16] = (v > 20.f) ? v : __logf(1.f + __expf(v));
                }
            }
    } else {
        float* C = (float*)Cv;
#pragma unroll
        for (int i = 0; i < 4; ++i)
#pragma unroll
            for (int p = 0; p < 4; ++p) {
                int row = bm + wr * 64 + i * 16 + cr + p;
                float* Cp = C + (size_t)row * N + bn + wc * 64 + cc;
#pragma unroll
                for (int j = 0; j < 4; ++j)
                    Cp[j * 16] = acc[i][j][p];
            }
    }
}

// ------------------------- x_proj: tall-skinny split-K bf16 MFMA, no LDS
__global__ __launch_bounds__(256) void xproj_kernel(
    const short* __restrict__ A, const short* __restrict__ W,
    float* __restrict__ Xpart)
{
    int lane = threadIdx.x & 63, wv = threadIdx.x >> 6;
    int sk = blockIdx.x;
    int m0 = blockIdx.y * 64 + wv * 16;
    int fr = lane & 15, fk = (lane >> 4) * 8;
    const short* Ap = A + (size_t)(m0 + fr) * D_INNER + sk * XKC + fk;
    const short* Wp = W + (size_t)fr * D_INNER + sk * XKC + fk;
    f32x4 acc[6] = {};
    for (int k = 0; k < XKC; k += 32) {
        short8v af = *(const short8v*)(Ap + k);
#pragma unroll
        for (int j = 0; j < 6; ++j) {
            short8v bf = *(const short8v*)(Wp + (size_t)j * 16 * D_INNER + k);
            acc[j] = __builtin_amdgcn_mfma_f32_16x16x32_bf16(af, bf, acc[j], 0, 0, 0);
        }
    }
    int cr = (lane >> 4) * 4, cc = lane & 15;
    float* Op = Xpart + ((size_t)sk * (BQ * LQ) + m0 + cr) * 96 + cc;
#pragma unroll
    for (int j = 0; j < 6; ++j)
#pragma unroll
        for (int p = 0; p < 4; ++p)
            Op[(size_t)p * 96 + j * 16] = acc[j][p];
}

// reduce split-K partials -> xdbl f32; also emit compact bf16 dt_r [BL][64]
__global__ __launch_bounds__(256) void xreduce_kernel(
    const float* __restrict__ Xpart, float* __restrict__ xdbl,
    short* __restrict__ dtr)
{
    size_t i = (size_t)blockIdx.x * 256 + threadIdx.x;
    float s = 0.f;
#pragma unroll
    for (int sk = 0; sk < XSPLITK; ++sk)
        s += Xpart[(size_t)sk * ((size_t)BQ * LQ * 96) + i];
    xdbl[i] = s;
    int col = (int)(i % 96);
    if (col < DT_RANK)
        dtr[(i / 96) * DT_RANK + col] = f2bf(s);
}

// --------------------------- causal conv + SiLU (bf16 in from uz, bf16 out)
__global__ __launch_bounds__(256) void conv_silu_kernel(
    const unsigned short* __restrict__ uz, short* __restrict__ outb,
    const float* __restrict__ w, const float* __restrict__ bias)
{
    int idx = blockIdx.x * 256 + threadIdx.x;
    int c = idx & (D_INNER - 1);
    int bl = idx / D_INNER;
    int l = bl & (LQ - 1);
    int b = bl / LQ;
    float acc = bias[c];
#pragma unroll
    for (int k = 0; k < D_CONV; ++k) {
        int ls = l - (D_CONV - 1) + k;
        if (ls >= 0)
            acc += bf2f(uz[((size_t)b * LQ + ls) * (2 * D_INNER) + c]) * w[c * D_CONV + k];
    }
    float val = acc / (1.f + __expf(-acc));
    outb[idx] = f2bf(val);
}

// -------------------------------------------- selective scan, chunked 3-phase
__global__ __launch_bounds__(256) void scan_phase1_kernel(
    const unsigned short* __restrict__ u, const float* __restrict__ dt,
    const float* __restrict__ xdbl, const float* __restrict__ A_log,
    float* __restrict__ Pbuf, float* __restrict__ Fbuf)
{
    __shared__ float S[CHUNK][D_STATE];
    int t = threadIdx.x;
    int d = blockIdx.x * 256 + t;
    int c = blockIdx.y;
    int b = blockIdx.z;
    int l0 = c * CHUNK;
    {   // stage B slice: 32 rows x 16 cols
        int row = t >> 3, cc2 = (t & 7) * 2;
        const float* src = xdbl + ((size_t)(b * LQ + l0 + row)) * 96 + DT_RANK + cc2;
        *(float2*)&S[row][cc2] = *(const float2*)src;
    }
    float A[D_STATE], h[D_STATE], P[D_STATE];
    {
        const float4* ap = (const float4*)(A_log + (size_t)d * D_STATE);
#pragma unroll
        for (int g = 0; g < 4; ++g) {
            float4 a = ap[g];
            A[g*4+0] = -__expf(a.x); A[g*4+1] = -__expf(a.y);
            A[g*4+2] = -__expf(a.z); A[g*4+3] = -__expf(a.w);
        }
    }
#pragma unroll
    for (int n = 0; n < D_STATE; ++n) { h[n] = 0.f; P[n] = 1.f; }
    const unsigned short* up = u + ((size_t)b * LQ + l0) * D_INNER + d;
    const float* dtp = dt + ((size_t)b * LQ + l0) * D_INNER + d;
    __syncthreads();

    for (int l = 0; l < CHUNK; ++l) {
        float uv  = bf2f(up[(size_t)l * D_INNER]);
        float dtv = dtp[(size_t)l * D_INNER];
        float du = dtv * uv;
#pragma unroll
        for (int n4 = 0; n4 < D_STATE; n4 += 4) {
            float4 Bv = *(const float4*)&S[l][n4];
            float bb[4] = {Bv.x, Bv.y, Bv.z, Bv.w};
#pragma unroll
            for (int k = 0; k < 4; ++k) {
                int n = n4 + k;
                float dA = __expf(dtv * A[n]);
                P[n] *= dA;
                h[n] = dA * h[n] + du * bb[k];
            }
        }
    }
    size_t base = ((size_t)(b * NCHUNK + c) * D_STATE) * D_INNER + d;
#pragma unroll
    for (int n = 0; n < D_STATE; ++n) {
        Pbuf[base + (size_t)n * D_INNER] = P[n];
        Fbuf[base + (size_t)n * D_INNER] = h[n];
    }
}

__global__ __launch_bounds__(256) void scan_phase2_kernel(
    const float* __restrict__ Pbuf, float* __restrict__ Fbuf)
{
    int d = blockIdx.x * 256 + threadIdx.x;
    int n = blockIdx.y;
    int b = blockIdx.z;
    float hinit = 0.f;
    for (int c = 0; c < NCHUNK; ++c) {
        size_t idx = ((size_t)(b * NCHUNK + c) * D_STATE + n) * D_INNER + d;
        float P = Pbuf[idx];
        float F = Fbuf[idx];
        Fbuf[idx] = hinit;
        hinit = P * hinit + F;
    }
}

// phase 3: LDS-staged B+C (XOR-swizzled), native exp, fused silu(z) gate,
// bf16 output for out_proj. z read as bf16 from the fused uz buffer.
__global__ __launch_bounds__(256) void scan_phase3_kernel(
    const unsigned short* __restrict__ u, const float* __restrict__ dt,
    const float* __restrict__ xdbl, const float* __restrict__ A_log,
    const float* __restrict__ Dp, const float* __restrict__ Hinit,
    const unsigned short* __restrict__ uz, short* __restrict__ yout)
{
    __shared__ float S[CHUNK][32];
    int t = threadIdx.x;
    int d = blockIdx.x * 256 + t;
    int c = blockIdx.y;
    int b = blockIdx.z;
    int l0 = c * CHUNK;
    {   // stage B+C slice: 32 rows x 32 cols, XOR-swizzled
        int row = t >> 3, cg = (t & 7) * 4;
        const float* src = xdbl + ((size_t)(b * LQ + l0 + row)) * 96 + DT_RANK + cg;
        *(float4*)&S[row][cg ^ ((row & 7) << 2)] = *(const float4*)src;
    }
    float A[D_STATE], h[D_STATE];
    {
        const float4* ap = (const float4*)(A_log + (size_t)d * D_STATE);
#pragma unroll
        for (int g = 0; g < 4; ++g) {
            float4 a = ap[g];
            A[g*4+0] = -__expf(a.x); A[g*4+1] = -__expf(a.y);
            A[g*4+2] = -__expf(a.z); A[g*4+3] = -__expf(a.w);
        }
    }
    size_t base = ((size_t)(b * NCHUNK + c) * D_STATE) * D_INNER + d;
#pragma unroll
    for (int n = 0; n < D_STATE; ++n)
        h[n] = Hinit[base + (size_t)n * D_INNER];
    float Dd = Dp[d];
    const unsigned short* up = u + ((size_t)b * LQ + l0) * D_INNER + d;
    const float* dtp = dt + ((size_t)b * LQ + l0) * D_INNER + d;
    const unsigned short* zp = uz + ((size_t)b * LQ + l0) * (2 * D_INNER) + D_INNER + d;
    short* yp = yout + ((size_t)b * LQ + l0) * D_INNER + d;
    __syncthreads();

    for (int l = 0; l < CHUNK; ++l) {
        float uv  = bf2f(up[(size_t)l * D_INNER]);
        float dtv = dtp[(size_t)l * D_INNER];
        float du = dtv * uv;
        float acc = 0.f;
        int sw = (l & 7) << 2;
#pragma unroll
        for (int n4 = 0; n4 < D_STATE; n4 += 4) {
            float4 Bv = *(const float4*)&S[l][n4 ^ sw];
            float4 Cv = *(const float4*)&S[l][(16 + n4) ^ sw];
            float bb[4] = {Bv.x, Bv.y, Bv.z, Bv.w};
            float cc[4] = {Cv.x, Cv.y, Cv.z, Cv.w};
#pragma unroll
            for (int k = 0; k < 4; ++k) {
                int n = n4 + k;
                float dA = __expf(dtv * A[n]);
                h[n] = dA * h[n] + du * bb[k];
                acc += h[n] * cc[k];
            }
        }
        float y = acc + uv * Dd;
        float zv = bf2f(zp[(size_t)l * (2 * D_INNER)]);
        float g = zv / (1.f + __expf(-zv));
        yp[(size_t)l * D_INNER] = f2bf(y * g);
    }
}

// --------------------------------------------------- f32 -> bf16 conversion
__global__ __launch_bounds__(256) void convert_bf16_kernel(
    const float* __restrict__ in, short* __restrict__ out)
{
    int i = (blockIdx.x * 256 + threadIdx.x) * 4;
    float4 v = *(const float4*)(in + i);
    short4 o = make_short4(f2bf(v.x), f2bf(v.y), f2bf(v.z), f2bf(v.w));
    *(short4*)(out + i) = o;
}

// ---------------------------------------------------------------- launcher
extern "C" void kernel_launch(void* const* d_in, const int* in_sizes, int n_in,
                              void* d_out, int out_size, void* d_ws, size_t ws_size,
                              hipStream_t stream)
{
    const float* x        = (const float*)d_in[0];
    const float* norm_w   = (const float*)d_in[2];
    const float* norm_b   = (const float*)d_in[3];
    const float* in_proj  = (const float*)d_in[4];
    const float* conv_w   = (const float*)d_in[5];
    const float* conv_b   = (const float*)d_in[6];
    const float* x_proj   = (const float*)d_in[7];
    const float* dt_proj  = (const float*)d_in[8];
    const float* dt_projb = (const float*)d_in[9];
    const float* A_log    = (const float*)d_in[10];
    const float* Dp       = (const float*)d_in[11];
    const float* out_proj = (const float*)d_in[12];
    float* out = (float*)d_out;
    float* ws  = (float*)d_ws;

    const size_t BL   = (size_t)BQ * LQ;            // 4096
    const size_t BLDM = BL * D_MODEL;
    const size_t BLDI = BL * D_INNER;
    const int IN_W  = 2 * D_INNER * D_MODEL;
    const int OUT_W = D_MODEL * D_INNER;
    const int XP_W  = 96 * D_INNER;
    const int DT_W  = D_INNER * DT_RANK;

    size_t o = 0;
    float* Pbuf  = ws + o; o += BLDM;                // also: hnb (bf16)
    short* uzb   = (short*)(ws + o); o += BL * 2 * D_INNER / 2;  // bf16 [BL][4096]
    float* dtb   = ws + o; o += BLDI;
    float* xdbl  = ws + o; o += BL * 96;
    float* h1    = ws + o; o += BLDM;                // also: Xpart
    float* Fbuf  = ws + o; o += BLDM;
    short* ucx   = (short*)(ws + o); o += BLDI / 2;  // bf16 u; then gated bf16 y
    short* dtr   = (short*)(ws + o); o += BL * DT_RANK / 2;
    short* wbuf  = (short*)(ws + o);
    o += (size_t)(IN_W + OUT_W + XP_W + DT_W + 1) / 2;

    short* hnb = (short*)Pbuf;
    float* Xpart = h1;

    for (int layer = 0; layer < DEPTH; ++layer) {
        const float* src = (layer == 0) ? x : h1;
        float* dst = (layer == DEPTH - 1) ? out : h1;

        layernorm_kernel<<<(int)BL, 256, 0, stream>>>(
            src, norm_w + (size_t)layer * D_MODEL, norm_b + (size_t)layer * D_MODEL, hnb);

        convert_bf16_kernel<<<IN_W / 1024, 256, 0, stream>>>(
            in_proj + (size_t)layer * IN_W, wbuf);
        convert_bf16_kernel<<<OUT_W / 1024, 256, 0, stream>>>(
            out_proj + (size_t)layer * OUT_W, wbuf + IN_W);
        convert_bf16_kernel<<<XP_W / 1024, 256, 0, stream>>>(
            x_proj + (size_t)layer * XP_W, wbuf + IN_W + OUT_W);
        convert_bf16_kernel<<<DT_W / 1024, 256, 0, stream>>>(
            dt_proj + (size_t)layer * DT_W, wbuf + IN_W + OUT_W + XP_W);

        // fused in_proj: N = 2*D_INNER, bf16 output (u | z)
        gemm_bf16_kernel<<<(int)(BL / 128) * (2 * D_INNER / 128), 256, 0, stream>>>(
            hnb, wbuf, uzb, (int)BL, 2 * D_INNER, D_MODEL, nullptr, 2);

        conv_silu_kernel<<<(int)(BLDI / 256), 256, 0, stream>>>(
            (const unsigned short*)uzb, ucx,
            conv_w + (size_t)layer * D_INNER * D_CONV,
            conv_b + (size_t)layer * D_INNER);

        xproj_kernel<<<dim3(XSPLITK, BL / 64), 256, 0, stream>>>(
            ucx, wbuf + IN_W + OUT_W, Xpart);
        xreduce_kernel<<<(int)(BL * 96 / 256), 256, 0, stream>>>(Xpart, xdbl, dtr);

        gemm_bf16_kernel<<<(int)(BL / 128) * (D_INNER / 128), 256, 0, stream>>>(
            dtr, wbuf + IN_W + OUT_W + XP_W, dtb, (int)BL, D_INNER, DT_RANK,
            dt_projb + (size_t)layer * D_INNER, 1);

        const float* Al = A_log + (size_t)layer * D_INNER * D_STATE;
        scan_phase1_kernel<<<dim3(D_INNER / 256, NCHUNK, BQ), 256, 0, stream>>>(
            (const unsigned short*)ucx, dtb, xdbl, Al, Pbuf, Fbuf);
        scan_phase2_kernel<<<dim3(D_INNER / 256, D_STATE, BQ), 256, 0, stream>>>(
            Pbuf, Fbuf);
        scan_phase3_kernel<<<dim3(D_INNER / 256, NCHUNK, BQ), 256, 0, stream>>>(
            (const unsigned short*)ucx, dtb, xdbl, Al,
            Dp + (size_t)layer * D_INNER, Fbuf,
            (const unsigned short*)uzb, (short*)ucx);

        gemm_bf16_kernel<<<(int)(BL / 128) * (D_MODEL / 128), 256, 0, stream>>>(
            ucx, wbuf + IN_W, dst, (int)BL, D_MODEL, D_INNER, nullptr, 0);
    }
}

// Round 8
// 516.794 us; speedup vs baseline: 11.0690x; 1.0570x over previous
//
#include <hip/hip_runtime.h>
#include <hip/hip_bf16.h>
#include <math.h>

#define BQ 2
#define LQ 2048
#define D_MODEL 1024
#define D_INNER 2048
#define D_STATE 16
#define DT_RANK 64
#define D_CONV 4
#define DEPTH 2
#define NCHUNK 64
#define CHUNK 32
#define XSPLITK 8
#define XKC (D_INNER / XSPLITK)   // 256

typedef __attribute__((ext_vector_type(8))) short short8v;  // 8 bf16 (4 VGPRs)
typedef __attribute__((ext_vector_type(4))) float f32x4;

__device__ __forceinline__ short f2bf(float f) {
    union { float f; unsigned u; } v; v.f = f;
    unsigned r = v.u + 0x7fffu + ((v.u >> 16) & 1u);   // RNE
    return (short)(r >> 16);
}

__device__ __forceinline__ float bf2f(unsigned short s) {
    union { unsigned u; float f; } v; v.u = ((unsigned)s) << 16;
    return v.f;
}

__device__ __forceinline__ void async16(void* lds, const void* gp) {
    __builtin_amdgcn_global_load_lds(
        (const __attribute__((address_space(1))) void*)gp,
        (__attribute__((address_space(3))) void*)lds, 16, 0, 0);
}

// ------------------------------------------------- LayerNorm (bf16 output)
__global__ __launch_bounds__(256) void layernorm_kernel(
    const float* __restrict__ x, const float* __restrict__ w,
    const float* __restrict__ b, short* __restrict__ out)
{
    __shared__ float red[8];
    int row = blockIdx.x;
    const float* xr = x + (size_t)row * D_MODEL;
    float v[4];
    float s = 0.f, sq = 0.f;
#pragma unroll
    for (int i = 0; i < 4; ++i) {
        v[i] = xr[threadIdx.x + i * 256];
        s += v[i];
        sq += v[i] * v[i];
    }
#pragma unroll
    for (int off = 32; off; off >>= 1) {
        s += __shfl_down(s, off, 64);
        sq += __shfl_down(sq, off, 64);
    }
    int wid = threadIdx.x >> 6, lane = threadIdx.x & 63;
    if (!lane) { red[wid] = s; red[4 + wid] = sq; }
    __syncthreads();
    s = red[0] + red[1] + red[2] + red[3];
    sq = red[4] + red[5] + red[6] + red[7];
    float mu = s * (1.f / D_MODEL);
    float var = sq * (1.f / D_MODEL) - mu * mu;
    float rstd = rsqrtf(var + 1e-5f);
#pragma unroll
    for (int i = 0; i < 4; ++i) {
        int c = threadIdx.x + i * 256;
        out[(size_t)row * D_MODEL + c] = f2bf((v[i] - mu) * rstd * w[c] + b[c]);
    }
}

// =================== 256x256 8-phase bf16 GEMM (T1+T2+T3+T4+T5) ===========
// C[M,N] bf16 = A[M,K] bf16 @ W[N,K]^T bf16. M,N mult of 256, K mult of 128.
// 512 thr / 8 waves (2Mx4N), BK=64, 128KB LDS dbuf, chunk-XOR swizzle,
// counted vmcnt (4) at ph0/ph4, raw s_barrier, setprio around MFMA.
__global__ __launch_bounds__(512) void gemm256_bf16_kernel(
    const short* __restrict__ A, const short* __restrict__ W,
    short* __restrict__ C, int M, int N, int K)
{
    __shared__ __align__(16) short lds[65536];   // 128 KB
    const int tid = threadIdx.x;
    const int lane = tid & 63;
    const int w = tid >> 6;              // 0..7
    const int wr = w >> 2, wc = w & 3;   // 2 x 4 wave grid

    int nbx = N >> 8;
    int nwg = (M >> 8) * nbx;
    int q = nwg >> 3;                    // nwg % 8 == 0
    int wg = ((int)blockIdx.x & 7) * q + ((int)blockIdx.x >> 3);
    int bx = wg % nbx, by = wg / nbx;
    int bm = by << 8, bn = bx << 8;

    const int fr = lane & 15;
    const int kl = lane >> 4;            // 0..3 (16B chunk within 32-elem k)
    const int srow = lane >> 3;          // staging: 0..7
    const int schunk = (lane & 7) ^ (srow & 7);

    f32x4 acc[8][4] = {};

    // stage one half-tile (128x64 bf16) : 2 x global_load_lds per thread
    auto STAGE = [&](int isA, int buf, int half, int kt) {
        const short* gp = isA ? A : W;
        int tile0 = isA ? bm : bn;
        int base = (isA ? 0 : 32768) + (buf * 2 + half) * 8192;
        int ko = kt << 6;
#pragma unroll
        for (int s = 0; s < 2; ++s) {
            int row = half * 128 + s * 64 + w * 8 + srow;
            const short* src = gp + (size_t)(tile0 + row) * K + ko + schunk * 8;
            async16(&lds[base + s * 4096 + w * 512], src);
        }
    };

    // one compute phase: quadrant (mh, nh) of buffer buf
    auto PHASE = [&](int buf, int mh, int nh) {
        short8v af[4][2], bf[2][2];
        int abase = (buf * 2 + mh) * 8192;
        int bbase = 32768 + (buf * 2 + nh) * 8192;
#pragma unroll
        for (int i = 0; i < 4; ++i) {
            int rl = wr * 64 + i * 16 + fr;
            int rsw = rl & 7;
#pragma unroll
            for (int ks = 0; ks < 2; ++ks)
                af[i][ks] = *(const short8v*)&lds[abase + rl * 64 + (((ks * 4 + kl) ^ rsw) * 8)];
        }
#pragma unroll
        for (int j = 0; j < 2; ++j) {
            int rl = wc * 32 + j * 16 + fr;
            int rsw = rl & 7;
#pragma unroll
            for (int ks = 0; ks < 2; ++ks)
                bf[j][ks] = *(const short8v*)&lds[bbase + rl * 64 + (((ks * 4 + kl) ^ rsw) * 8)];
        }
        asm volatile("s_waitcnt lgkmcnt(0)" ::: "memory");
        __builtin_amdgcn_sched_barrier(0);
        __builtin_amdgcn_s_setprio(1);
#pragma unroll
        for (int i = 0; i < 4; ++i)
#pragma unroll
            for (int j = 0; j < 2; ++j)
#pragma unroll
                for (int ks = 0; ks < 2; ++ks)
                    acc[mh * 4 + i][nh * 2 + j] = __builtin_amdgcn_mfma_f32_16x16x32_bf16(
                        af[i][ks], bf[j][ks], acc[mh * 4 + i][nh * 2 + j], 0, 0, 0);
        __builtin_amdgcn_s_setprio(0);
    };

#define GBAR  __builtin_amdgcn_s_barrier(); __builtin_amdgcn_sched_barrier(0);

    // prologue: kt0 -> buf0 (all 4 halves), kt1 -> buf1 (A0,B0)
    STAGE(1, 0, 0, 0); STAGE(0, 0, 0, 0);
    STAGE(1, 0, 1, 0); STAGE(0, 0, 1, 0);
    STAGE(1, 1, 0, 1); STAGE(0, 1, 0, 1);

    int T = K >> 7;                       // iterations of 2 K-tiles
    for (int t = 0; t < T; ++t) {
        int last = (t == T - 1);
        // ph0: X(0,0); stage A1Y (kt=2t+1)
        asm volatile("s_waitcnt vmcnt(4)" ::: "memory");
        STAGE(1, 1, 1, 2 * t + 1);
        GBAR; PHASE(0, 0, 0); GBAR;
        // ph1: X(0,1); stage B1Y
        STAGE(0, 1, 1, 2 * t + 1);
        GBAR; PHASE(0, 0, 1); GBAR;
        // ph2: X(1,0); stage A0X' (kt=2t+2)
        if (!last) STAGE(1, 0, 0, 2 * t + 2);
        GBAR; PHASE(0, 1, 0); GBAR;
        // ph3: X(1,1); stage B0X'
        if (!last) STAGE(0, 0, 0, 2 * t + 2);
        GBAR; PHASE(0, 1, 1); GBAR;
        // ph4: Y(0,0); vmcnt; stage A1X'
        if (last) { asm volatile("s_waitcnt vmcnt(0)" ::: "memory"); }
        else      { asm volatile("s_waitcnt vmcnt(4)" ::: "memory"); }
        if (!last) STAGE(1, 0, 1, 2 * t + 2);
        GBAR; PHASE(1, 0, 0); GBAR;
        // ph5: Y(0,1); stage B1X'
        if (!last) STAGE(0, 0, 1, 2 * t + 2);
        GBAR; PHASE(1, 0, 1); GBAR;
        // ph6: Y(1,0); stage A0Y' (kt=2t+3)
        if (!last) STAGE(1, 1, 0, 2 * t + 3);
        GBAR; PHASE(1, 1, 0); GBAR;
        // ph7: Y(1,1); stage B0Y'
        if (!last) STAGE(0, 1, 0, 2 * t + 3);
        GBAR; PHASE(1, 1, 1); GBAR;
    }
#undef GBAR

    int cr = (lane >> 4) * 4, cc = lane & 15;
#pragma unroll
    for (int i8 = 0; i8 < 8; ++i8) {
        int mh = i8 >> 2, ii = i8 & 3;
        int row0 = bm + mh * 128 + wr * 64 + ii * 16 + cr;
#pragma unroll
        for (int p = 0; p < 4; ++p) {
            short* Cp = C + (size_t)(row0 + p) * N + bn;
#pragma unroll
            for (int j4 = 0; j4 < 4; ++j4) {
                int nh = j4 >> 1, jj = j4 & 1;
                Cp[nh * 128 + wc * 32 + jj * 16 + cc] = f2bf(acc[i8][j4][p]);
            }
        }
    }
}

// ---------------- 128x128 bf16 MFMA GEMM: dbuf stage-early + XCD swizzle
// epilogue 0: f32 store; 1: softplus(acc+bias[col]) f32; 2: bf16 store
__global__ __launch_bounds__(256) void gemm_bf16_kernel(
    const short* __restrict__ A, const short* __restrict__ W,
    void* __restrict__ Cv, int M, int N, int K,
    const float* __restrict__ bias, int epilogue)
{
    __shared__ __align__(16) short As[2][128 * 32];
    __shared__ __align__(16) short Bs[2][128 * 32];
    int tid = threadIdx.x;
    int lane = tid & 63, wv = tid >> 6;
    int nbx = N >> 7;
    int nwg = (M >> 7) * nbx;
    int q = nwg >> 3;
    int wg = ((int)blockIdx.x & 7) * q + ((int)blockIdx.x >> 3);
    int bx = wg % nbx, by = wg / nbx;
    int bm = by * 128, bn = bx * 128;
    int wr = wv >> 1, wc = wv & 1;

    f32x4 acc[4][4] = {};

    const short* Ag = A + (size_t)(bm + wv * 16 + (lane >> 2)) * K + (lane & 3) * 8;
    const short* Bg = W + (size_t)(bn + wv * 16 + (lane >> 2)) * K + (lane & 3) * 8;
    size_t rowskip = (size_t)64 * K;
    int lo = (wv * 16) * 32;

    int fr = lane & 15, fk = (lane >> 4) * 8;
    int NT = K >> 5;

    async16(&As[0][lo], Ag);
    async16(&As[0][lo + 64 * 32], Ag + rowskip);
    async16(&Bs[0][lo], Bg);
    async16(&Bs[0][lo + 64 * 32], Bg + rowskip);
    __syncthreads();

    int cur = 0;
    for (int t = 0; t < NT; ++t) {
        if (t + 1 < NT) {
            int k0 = (t + 1) << 5;
            int nb = cur ^ 1;
            async16(&As[nb][lo], Ag + k0);
            async16(&As[nb][lo + 64 * 32], Ag + rowskip + k0);
            async16(&Bs[nb][lo], Bg + k0);
            async16(&Bs[nb][lo + 64 * 32], Bg + rowskip + k0);
        }
        short8v af[4], bf[4];
#pragma unroll
        for (int i = 0; i < 4; ++i)
            af[i] = *(const short8v*)&As[cur][(wr * 64 + i * 16 + fr) * 32 + fk];
#pragma unroll
        for (int j = 0; j < 4; ++j)
            bf[j] = *(const short8v*)&Bs[cur][(wc * 64 + j * 16 + fr) * 32 + fk];
#pragma unroll
        for (int i = 0; i < 4; ++i)
#pragma unroll
            for (int j = 0; j < 4; ++j)
                acc[i][j] = __builtin_amdgcn_mfma_f32_16x16x32_bf16(
                    af[i], bf[j], acc[i][j], 0, 0, 0);
        __syncthreads();
        cur ^= 1;
    }

    int cr = (lane >> 4) * 4, cc = lane & 15;
    if (epilogue == 2) {
        short* C = (short*)Cv;
#pragma unroll
        for (int i = 0; i < 4; ++i)
#pragma unroll
            for (int p = 0; p < 4; ++p) {
                int row = bm + wr * 64 + i * 16 + cr + p;
                short* Cp = C + (size_t)row * N + bn + wc * 64 + cc;
#pragma unroll
                for (int j = 0; j < 4; ++j)
                    Cp[j * 16] = f2bf(acc[i][j][p]);
            }
    } else if (epilogue == 1) {
        float* C = (float*)Cv;
#pragma unroll
        for (int i = 0; i < 4; ++i)
#pragma unroll
            for (int p = 0; p < 4; ++p) {
                int row = bm + wr * 64 + i * 16 + cr + p;
                float* Cp = C + (size_t)row * N + bn + wc * 64 + cc;
#pragma unroll
                for (int j = 0; j < 4; ++j) {
                    float v = acc[i][j][p] + bias[bn + wc * 64 + cc + j * 16];
                    Cp[j * 16] = (v > 20.f) ? v : __logf(1.f + __expf(v));
                }
            }
    } else {
        float* C = (float*)Cv;
#pragma unroll
        for (int i = 0; i < 4; ++i)
#pragma unroll
            for (int p = 0; p < 4; ++p) {
                int row = bm + wr * 64 + i * 16 + cr + p;
                float* Cp = C + (size_t)row * N + bn + wc * 64 + cc;
#pragma unroll
                for (int j = 0; j < 4; ++j)
                    Cp[j * 16] = acc[i][j][p];
            }
    }
}

// ------------------------- x_proj: tall-skinny split-K bf16 MFMA, no LDS
__global__ __launch_bounds__(256) void xproj_kernel(
    const short* __restrict__ A, const short* __restrict__ W,
    float* __restrict__ Xpart)
{
    int lane = threadIdx.x & 63, wv = threadIdx.x >> 6;
    int sk = blockIdx.x;
    int m0 = blockIdx.y * 64 + wv * 16;
    int fr = lane & 15, fk = (lane >> 4) * 8;
    const short* Ap = A + (size_t)(m0 + fr) * D_INNER + sk * XKC + fk;
    const short* Wp = W + (size_t)fr * D_INNER + sk * XKC + fk;
    f32x4 acc[6] = {};
    for (int k = 0; k < XKC; k += 32) {
        short8v af = *(const short8v*)(Ap + k);
#pragma unroll
        for (int j = 0; j < 6; ++j) {
            short8v bf = *(const short8v*)(Wp + (size_t)j * 16 * D_INNER + k);
            acc[j] = __builtin_amdgcn_mfma_f32_16x16x32_bf16(af, bf, acc[j], 0, 0, 0);
        }
    }
    int cr = (lane >> 4) * 4, cc = lane & 15;
    float* Op = Xpart + ((size_t)sk * (BQ * LQ) + m0 + cr) * 96 + cc;
#pragma unroll
    for (int j = 0; j < 6; ++j)
#pragma unroll
        for (int p = 0; p < 4; ++p)
            Op[(size_t)p * 96 + j * 16] = acc[j][p];
}

// reduce split-K partials -> xdbl f32; also emit compact bf16 dt_r [BL][64]
__global__ __launch_bounds__(256) void xreduce_kernel(
    const float* __restrict__ Xpart, float* __restrict__ xdbl,
    short* __restrict__ dtr)
{
    size_t i = (size_t)blockIdx.x * 256 + threadIdx.x;
    float s = 0.f;
#pragma unroll
    for (int sk = 0; sk < XSPLITK; ++sk)
        s += Xpart[(size_t)sk * ((size_t)BQ * LQ * 96) + i];
    xdbl[i] = s;
    int col = (int)(i % 96);
    if (col < DT_RANK)
        dtr[(i / 96) * DT_RANK + col] = f2bf(s);
}

// --------------------------- causal conv + SiLU (bf16 in from uz, bf16 out)
__global__ __launch_bounds__(256) void conv_silu_kernel(
    const unsigned short* __restrict__ uz, short* __restrict__ outb,
    const float* __restrict__ w, const float* __restrict__ bias)
{
    int idx = blockIdx.x * 256 + threadIdx.x;
    int c = idx & (D_INNER - 1);
    int bl = idx / D_INNER;
    int l = bl & (LQ - 1);
    int b = bl / LQ;
    float acc = bias[c];
#pragma unroll
    for (int k = 0; k < D_CONV; ++k) {
        int ls = l - (D_CONV - 1) + k;
        if (ls >= 0)
            acc += bf2f(uz[((size_t)b * LQ + ls) * (2 * D_INNER) + c]) * w[c * D_CONV + k];
    }
    float val = acc / (1.f + __expf(-acc));
    outb[idx] = f2bf(val);
}

// -------------------------------------------- selective scan, chunked 3-phase
__global__ __launch_bounds__(256) void scan_phase1_kernel(
    const unsigned short* __restrict__ u, const float* __restrict__ dt,
    const float* __restrict__ xdbl, const float* __restrict__ A_log,
    float* __restrict__ Pbuf, float* __restrict__ Fbuf)
{
    __shared__ float S[CHUNK][D_STATE];
    int t = threadIdx.x;
    int d = blockIdx.x * 256 + t;
    int c = blockIdx.y;
    int b = blockIdx.z;
    int l0 = c * CHUNK;
    {
        int row = t >> 3, cc2 = (t & 7) * 2;
        const float* src = xdbl + ((size_t)(b * LQ + l0 + row)) * 96 + DT_RANK + cc2;
        *(float2*)&S[row][cc2] = *(const float2*)src;
    }
    float A[D_STATE], h[D_STATE], P[D_STATE];
    {
        const float4* ap = (const float4*)(A_log + (size_t)d * D_STATE);
#pragma unroll
        for (int g = 0; g < 4; ++g) {
            float4 a = ap[g];
            A[g*4+0] = -__expf(a.x); A[g*4+1] = -__expf(a.y);
            A[g*4+2] = -__expf(a.z); A[g*4+3] = -__expf(a.w);
        }
    }
#pragma unroll
    for (int n = 0; n < D_STATE; ++n) { h[n] = 0.f; P[n] = 1.f; }
    const unsigned short* up = u + ((size_t)b * LQ + l0) * D_INNER + d;
    const float* dtp = dt + ((size_t)b * LQ + l0) * D_INNER + d;
    __syncthreads();

    for (int l = 0; l < CHUNK; ++l) {
        float uv  = bf2f(up[(size_t)l * D_INNER]);
        float dtv = dtp[(size_t)l * D_INNER];
        float du = dtv * uv;
#pragma unroll
        for (int n4 = 0; n4 < D_STATE; n4 += 4) {
            float4 Bv = *(const float4*)&S[l][n4];
            float bb[4] = {Bv.x, Bv.y, Bv.z, Bv.w};
#pragma unroll
            for (int k = 0; k < 4; ++k) {
                int n = n4 + k;
                float dA = __expf(dtv * A[n]);
                P[n] *= dA;
                h[n] = dA * h[n] + du * bb[k];
            }
        }
    }
    size_t base = ((size_t)(b * NCHUNK + c) * D_STATE) * D_INNER + d;
#pragma unroll
    for (int n = 0; n < D_STATE; ++n) {
        Pbuf[base + (size_t)n * D_INNER] = P[n];
        Fbuf[base + (size_t)n * D_INNER] = h[n];
    }
}

__global__ __launch_bounds__(256) void scan_phase2_kernel(
    const float* __restrict__ Pbuf, float* __restrict__ Fbuf)
{
    int d = blockIdx.x * 256 + threadIdx.x;
    int n = blockIdx.y;
    int b = blockIdx.z;
    float hinit = 0.f;
    for (int c = 0; c < NCHUNK; ++c) {
        size_t idx = ((size_t)(b * NCHUNK + c) * D_STATE + n) * D_INNER + d;
        float P = Pbuf[idx];
        float F = Fbuf[idx];
        Fbuf[idx] = hinit;
        hinit = P * hinit + F;
    }
}

// phase 3: LDS-staged B+C (XOR-swizzled), native exp, fused silu(z) gate,
// bf16 output for out_proj. z read as bf16 from the fused uz buffer.
__global__ __launch_bounds__(256) void scan_phase3_kernel(
    const unsigned short* __restrict__ u, const float* __restrict__ dt,
    const float* __restrict__ xdbl, const float* __restrict__ A_log,
    const float* __restrict__ Dp, const float* __restrict__ Hinit,
    const unsigned short* __restrict__ uz, short* __restrict__ yout)
{
    __shared__ float S[CHUNK][32];
    int t = threadIdx.x;
    int d = blockIdx.x * 256 + t;
    int c = blockIdx.y;
    int b = blockIdx.z;
    int l0 = c * CHUNK;
    {
        int row = t >> 3, cg = (t & 7) * 4;
        const float* src = xdbl + ((size_t)(b * LQ + l0 + row)) * 96 + DT_RANK + cg;
        *(float4*)&S[row][cg ^ ((row & 7) << 2)] = *(const float4*)src;
    }
    float A[D_STATE], h[D_STATE];
    {
        const float4* ap = (const float4*)(A_log + (size_t)d * D_STATE);
#pragma unroll
        for (int g = 0; g < 4; ++g) {
            float4 a = ap[g];
            A[g*4+0] = -__expf(a.x); A[g*4+1] = -__expf(a.y);
            A[g*4+2] = -__expf(a.z); A[g*4+3] = -__expf(a.w);
        }
    }
    size_t base = ((size_t)(b * NCHUNK + c) * D_STATE) * D_INNER + d;
#pragma unroll
    for (int n = 0; n < D_STATE; ++n)
        h[n] = Hinit[base + (size_t)n * D_INNER];
    float Dd = Dp[d];
    const unsigned short* up = u + ((size_t)b * LQ + l0) * D_INNER + d;
    const float* dtp = dt + ((size_t)b * LQ + l0) * D_INNER + d;
    const unsigned short* zp = uz + ((size_t)b * LQ + l0) * (2 * D_INNER) + D_INNER + d;
    short* yp = yout + ((size_t)b * LQ + l0) * D_INNER + d;
    __syncthreads();

    for (int l = 0; l < CHUNK; ++l) {
        float uv  = bf2f(up[(size_t)l * D_INNER]);
        float dtv = dtp[(size_t)l * D_INNER];
        float du = dtv * uv;
        float acc = 0.f;
        int sw = (l & 7) << 2;
#pragma unroll
        for (int n4 = 0; n4 < D_STATE; n4 += 4) {
            float4 Bv = *(const float4*)&S[l][n4 ^ sw];
            float4 Cv = *(const float4*)&S[l][(16 + n4) ^ sw];
            float bb[4] = {Bv.x, Bv.y, Bv.z, Bv.w};
            float cc[4] = {Cv.x, Cv.y, Cv.z, Cv.w};
#pragma unroll
            for (int k = 0; k < 4; ++k) {
                int n = n4 + k;
                float dA = __expf(dtv * A[n]);
                h[n] = dA * h[n] + du * bb[k];
                acc += h[n] * cc[k];
            }
        }
        float y = acc + uv * Dd;
        float zv = bf2f(zp[(size_t)l * (2 * D_INNER)]);
        float g = zv / (1.f + __expf(-zv));
        yp[(size_t)l * D_INNER] = f2bf(y * g);
    }
}

// --------------------------------------------------- f32 -> bf16 conversion
__global__ __launch_bounds__(256) void convert_bf16_kernel(
    const float* __restrict__ in, short* __restrict__ out)
{
    int i = (blockIdx.x * 256 + threadIdx.x) * 4;
    float4 v = *(const float4*)(in + i);
    short4 o = make_short4(f2bf(v.x), f2bf(v.y), f2bf(v.z), f2bf(v.w));
    *(short4*)(out + i) = o;
}

// ---------------------------------------------------------------- launcher
extern "C" void kernel_launch(void* const* d_in, const int* in_sizes, int n_in,
                              void* d_out, int out_size, void* d_ws, size_t ws_size,
                              hipStream_t stream)
{
    const float* x        = (const float*)d_in[0];
    const float* norm_w   = (const float*)d_in[2];
    const float* norm_b   = (const float*)d_in[3];
    const float* in_proj  = (const float*)d_in[4];
    const float* conv_w   = (const float*)d_in[5];
    const float* conv_b   = (const float*)d_in[6];
    const float* x_proj   = (const float*)d_in[7];
    const float* dt_proj  = (const float*)d_in[8];
    const float* dt_projb = (const float*)d_in[9];
    const float* A_log    = (const float*)d_in[10];
    const float* Dp       = (const float*)d_in[11];
    const float* out_proj = (const float*)d_in[12];
    float* out = (float*)d_out;
    float* ws  = (float*)d_ws;

    const size_t BL   = (size_t)BQ * LQ;            // 4096
    const size_t BLDM = BL * D_MODEL;
    const size_t BLDI = BL * D_INNER;
    const int IN_W  = 2 * D_INNER * D_MODEL;
    const int OUT_W = D_MODEL * D_INNER;
    const int XP_W  = 96 * D_INNER;
    const int DT_W  = D_INNER * DT_RANK;

    size_t o = 0;
    float* Pbuf  = ws + o; o += BLDM;                // also: hnb (bf16)
    short* uzb   = (short*)(ws + o); o += BL * 2 * D_INNER / 2;  // bf16 [BL][4096]
    float* dtb   = ws + o; o += BLDI;
    float* xdbl  = ws + o; o += BL * 96;
    float* h1    = ws + o; o += BLDM;                // also: Xpart
    float* Fbuf  = ws + o; o += BLDM;
    short* ucx   = (short*)(ws + o); o += BLDI / 2;  // bf16 u; then gated bf16 y
    short* dtr   = (short*)(ws + o); o += BL * DT_RANK / 2;
    short* wbuf  = (short*)(ws + o);
    o += (size_t)(IN_W + OUT_W + XP_W + DT_W + 1) / 2;

    short* hnb = (short*)Pbuf;
    float* Xpart = h1;

    for (int layer = 0; layer < DEPTH; ++layer) {
        const float* src = (layer == 0) ? x : h1;
        float* dst = (layer == DEPTH - 1) ? out : h1;

        layernorm_kernel<<<(int)BL, 256, 0, stream>>>(
            src, norm_w + (size_t)layer * D_MODEL, norm_b + (size_t)layer * D_MODEL, hnb);

        convert_bf16_kernel<<<IN_W / 1024, 256, 0, stream>>>(
            in_proj + (size_t)layer * IN_W, wbuf);
        convert_bf16_kernel<<<OUT_W / 1024, 256, 0, stream>>>(
            out_proj + (size_t)layer * OUT_W, wbuf + IN_W);
        convert_bf16_kernel<<<XP_W / 1024, 256, 0, stream>>>(
            x_proj + (size_t)layer * XP_W, wbuf + IN_W + OUT_W);
        convert_bf16_kernel<<<DT_W / 1024, 256, 0, stream>>>(
            dt_proj + (size_t)layer * DT_W, wbuf + IN_W + OUT_W + XP_W);

        // fused in_proj: M=4096, N=4096, K=1024, bf16 out -> 8-phase 256^2
        gemm256_bf16_kernel<<<(int)(BL / 256) * (2 * D_INNER / 256), 512, 0, stream>>>(
            hnb, wbuf, uzb, (int)BL, 2 * D_INNER, D_MODEL);

        conv_silu_kernel<<<(int)(BLDI / 256), 256, 0, stream>>>(
            (const unsigned short*)uzb, ucx,
            conv_w + (size_t)layer * D_INNER * D_CONV,
            conv_b + (size_t)layer * D_INNER);

        xproj_kernel<<<dim3(XSPLITK, BL / 64), 256, 0, stream>>>(
            ucx, wbuf + IN_W + OUT_W, Xpart);
        xreduce_kernel<<<(int)(BL * 96 / 256), 256, 0, stream>>>(Xpart, xdbl, dtr);

        gemm_bf16_kernel<<<(int)(BL / 128) * (D_INNER / 128), 256, 0, stream>>>(
            dtr, wbuf + IN_W + OUT_W + XP_W, dtb, (int)BL, D_INNER, DT_RANK,
            dt_projb + (size_t)layer * D_INNER, 1);

        const float* Al = A_log + (size_t)layer * D_INNER * D_STATE;
        scan_phase1_kernel<<<dim3(D_INNER / 256, NCHUNK, BQ), 256, 0, stream>>>(
            (const unsigned short*)ucx, dtb, xdbl, Al, Pbuf, Fbuf);
        scan_phase2_kernel<<<dim3(D_INNER / 256, D_STATE, BQ), 256, 0, stream>>>(
            Pbuf, Fbuf);
        scan_phase3_kernel<<<dim3(D_INNER / 256, NCHUNK, BQ), 256, 0, stream>>>(
            (const unsigned short*)ucx, dtb, xdbl, Al,
            Dp + (size_t)layer * D_INNER, Fbuf,
            (const unsigned short*)uzb, (short*)ucx);

        gemm_bf16_kernel<<<(int)(BL / 128) * (D_MODEL / 128), 256, 0, stream>>>(
            ucx, wbuf + IN_W, dst, (int)BL, D_MODEL, D_INNER, nullptr, 0);
    }
}